// Round 5
// baseline (2956.238 us; speedup 1.0000x reference)
//
#include <hip/hip_runtime.h>

#define D 128
#define TILE_ROWS 64
#define MLP_THREADS 512
#define SCAN_THREADS 1024
#define BK_NODES 128     // dst-nodes per coarse bucket
#define MAX_BKT 1024
#define EPB 16           // edges per thread in coarse passes
#define AGG_THREADS 512

typedef unsigned short ushort_t;
typedef unsigned int uint_t;

__device__ __forceinline__ ushort_t f2bf(float f) {
    uint_t u = __float_as_uint(f);
    u = u + 0x7FFFu + ((u >> 16) & 1u);   // round-to-nearest-even
    return (ushort_t)(u >> 16);
}
__device__ __forceinline__ float bf2f(ushort_t h) {
    return __uint_as_float(((uint_t)h) << 16);
}

// ===========================================================================
// cast: x (fp32) -> xh (bf16)
// ===========================================================================
__global__ void cast_kernel(const float* __restrict__ x, ushort_t* __restrict__ xh, int n4) {
    int i = blockIdx.x * blockDim.x + threadIdx.x;
    if (i < n4) {
        float4 v = reinterpret_cast<const float4*>(x)[i];
        ushort4 o;
        o.x = f2bf(v.x); o.y = f2bf(v.y); o.z = f2bf(v.z); o.w = f2bf(v.w);
        reinterpret_cast<ushort4*>(xh)[i] = o;
    }
}

// ===========================================================================
// Coarse bucketing (LDS-privatized): zero -> hist -> scan -> scatter
// pairs[] holds (src<<7)|(dst&127), grouped by coarse bucket (dst>>7).
// ===========================================================================
__global__ void zero_kernel(int* __restrict__ p, int n) {
    int i = blockIdx.x * blockDim.x + threadIdx.x;
    if (i < n) p[i] = 0;
}

__global__ void coarse_hist_kernel(const int* __restrict__ dsts,
                                   int* __restrict__ ghist, int ne, int nbkt) {
    __shared__ int h[MAX_BKT];
    for (int k = threadIdx.x; k < nbkt; k += blockDim.x) h[k] = 0;
    __syncthreads();
    int base = blockIdx.x * blockDim.x * EPB;
    for (int j = 0; j < EPB; ++j) {
        int e = base + j * blockDim.x + threadIdx.x;
        if (e < ne) atomicAdd(&h[dsts[e] >> 7], 1);
    }
    __syncthreads();
    for (int k = threadIdx.x; k < nbkt; k += blockDim.x)
        if (h[k]) atomicAdd(&ghist[k], h[k]);
}

__global__ __launch_bounds__(SCAN_THREADS) void coarse_scan_kernel(
    const int* __restrict__ ghist, int* __restrict__ cbase,
    int* __restrict__ ccursor, int nbkt) {
    __shared__ int sc[SCAN_THREADS];
    int t = threadIdx.x;
    int v = (t < nbkt) ? ghist[t] : 0;
    sc[t] = v;
    __syncthreads();
    for (int off = 1; off < SCAN_THREADS; off <<= 1) {
        int u = (t >= off) ? sc[t - off] : 0;
        __syncthreads();
        sc[t] += u;
        __syncthreads();
    }
    if (t < nbkt) { cbase[t] = sc[t] - v; ccursor[t] = sc[t] - v; }
    if (t == 0) cbase[nbkt] = sc[SCAN_THREADS - 1];
}

__global__ void coarse_scatter_kernel(const int* __restrict__ ei,
                                      int* __restrict__ ccursor,
                                      int* __restrict__ pairs, int ne, int nbkt) {
    __shared__ int h[MAX_BKT];
    __shared__ int cur[MAX_BKT];
    for (int k = threadIdx.x; k < nbkt; k += blockDim.x) h[k] = 0;
    __syncthreads();
    int base = blockIdx.x * blockDim.x * EPB;
    for (int j = 0; j < EPB; ++j) {
        int e = base + j * blockDim.x + threadIdx.x;
        if (e < ne) atomicAdd(&h[ei[ne + e] >> 7], 1);
    }
    __syncthreads();
    for (int k = threadIdx.x; k < nbkt; k += blockDim.x)
        cur[k] = h[k] ? atomicAdd(&ccursor[k], h[k]) : 0;
    __syncthreads();
    for (int j = 0; j < EPB; ++j) {
        int e = base + j * blockDim.x + threadIdx.x;
        if (e < ne) {
            int dst = ei[ne + e];
            int src = ei[e];
            int k = dst >> 7;
            int pos = atomicAdd(&cur[k], 1);
            pairs[pos] = (src << 7) | (dst & (BK_NODES - 1));
        }
    }
}

// ===========================================================================
// agg_pairs: one block per coarse bucket. fp32 LDS accumulator acc[128][128]
// (64 KB). Waves stream pairs in 64-edge chunks (coalesced load + shfl
// broadcast); per edge two 128B wave-gathers (dims lane / lane+64) and two
// conflict-free no-return LDS float atomics. Epilogue: out = x + acc.
// MODE 0: gather bf16 from xh; MODE 1: gather fp32 from x.
// ===========================================================================
template <int MODE>
__global__ __launch_bounds__(AGG_THREADS, 1) void agg_pairs_kernel(
    const float* __restrict__ x, const ushort_t* __restrict__ xh,
    const int* __restrict__ pairs, const int* __restrict__ cbase,
    float* __restrict__ out, int nnodes) {
    __shared__ float acc[BK_NODES][D];
    const int b = blockIdx.x;
    const int t = threadIdx.x;

    float4 z = make_float4(0.f, 0.f, 0.f, 0.f);
    for (int i = t; i < BK_NODES * D / 4; i += AGG_THREADS)
        reinterpret_cast<float4*>(&acc[0][0])[i] = z;
    __syncthreads();

    const int rbeg = cbase[b], rend = cbase[b + 1];
    const int lane = t & 63;
    const int wid = t >> 6;   // 8 waves

    for (int base = rbeg + (wid << 6); base < rend; base += (8 << 6)) {
        const int np = min(64, rend - base);
        int myp = (lane < np) ? pairs[base + lane] : 0;
        int j = 0;
        for (; j + 4 <= np; j += 4) {
            int p0 = __shfl(myp, j + 0);
            int p1 = __shfl(myp, j + 1);
            int p2 = __shfl(myp, j + 2);
            int p3 = __shfl(myp, j + 3);
            float a0, b0, a1, b1, a2, b2, a3, b3;
            if (MODE == 0) {
                const ushort_t* r0 = xh + (size_t)(p0 >> 7) * D;
                const ushort_t* r1 = xh + (size_t)(p1 >> 7) * D;
                const ushort_t* r2 = xh + (size_t)(p2 >> 7) * D;
                const ushort_t* r3 = xh + (size_t)(p3 >> 7) * D;
                ushort_t u0 = r0[lane], v0 = r0[lane + 64];
                ushort_t u1 = r1[lane], v1 = r1[lane + 64];
                ushort_t u2 = r2[lane], v2 = r2[lane + 64];
                ushort_t u3 = r3[lane], v3 = r3[lane + 64];
                a0 = bf2f(u0); b0 = bf2f(v0);
                a1 = bf2f(u1); b1 = bf2f(v1);
                a2 = bf2f(u2); b2 = bf2f(v2);
                a3 = bf2f(u3); b3 = bf2f(v3);
            } else {
                const float* r0 = x + (size_t)(p0 >> 7) * D;
                const float* r1 = x + (size_t)(p1 >> 7) * D;
                const float* r2 = x + (size_t)(p2 >> 7) * D;
                const float* r3 = x + (size_t)(p3 >> 7) * D;
                a0 = r0[lane]; b0 = r0[lane + 64];
                a1 = r1[lane]; b1 = r1[lane + 64];
                a2 = r2[lane]; b2 = r2[lane + 64];
                a3 = r3[lane]; b3 = r3[lane + 64];
            }
            atomicAdd(&acc[p0 & 127][lane], a0);
            atomicAdd(&acc[p0 & 127][lane + 64], b0);
            atomicAdd(&acc[p1 & 127][lane], a1);
            atomicAdd(&acc[p1 & 127][lane + 64], b1);
            atomicAdd(&acc[p2 & 127][lane], a2);
            atomicAdd(&acc[p2 & 127][lane + 64], b2);
            atomicAdd(&acc[p3 & 127][lane], a3);
            atomicAdd(&acc[p3 & 127][lane + 64], b3);
        }
        for (; j < np; ++j) {
            int p = __shfl(myp, j);
            float a, bb;
            if (MODE == 0) {
                const ushort_t* r = xh + (size_t)(p >> 7) * D;
                a = bf2f(r[lane]); bb = bf2f(r[lane + 64]);
            } else {
                const float* r = x + (size_t)(p >> 7) * D;
                a = r[lane]; bb = r[lane + 64];
            }
            atomicAdd(&acc[p & 127][lane], a);
            atomicAdd(&acc[p & 127][lane + 64], bb);
        }
    }
    __syncthreads();

    // epilogue: out[node] = x[node] + acc[row]
    for (int i = t; i < BK_NODES * D / 4; i += AGG_THREADS) {
        int row = i >> 5;
        int node = b * BK_NODES + row;
        if (node < nnodes) {
            float4 xv = reinterpret_cast<const float4*>(x + (size_t)node * D)[i & 31];
            float4 av = reinterpret_cast<float4*>(&acc[0][0])[i];
            float4 o;
            o.x = xv.x + av.x; o.y = xv.y + av.y;
            o.z = xv.z + av.z; o.w = xv.w + av.w;
            reinterpret_cast<float4*>(out + (size_t)node * D)[i & 31] = o;
        }
    }
}

// ===========================================================================
// Fallback: init + fp32 atomic scatter
// ===========================================================================
__global__ void init_kernel(const float* __restrict__ x, float* __restrict__ out, int n4) {
    int i = blockIdx.x * blockDim.x + threadIdx.x;
    if (i < n4) {
        reinterpret_cast<float4*>(out)[i] = reinterpret_cast<const float4*>(x)[i];
    }
}

__global__ void scatter_kernel(const float* __restrict__ x,
                               const int* __restrict__ ei,
                               float* __restrict__ out, int ne) {
    long long gid = (long long)blockIdx.x * blockDim.x + threadIdx.x;
    int e = (int)(gid >> 5);
    if (e >= ne) return;
    int d0 = ((int)gid & 31) * 4;
    int src = ei[e];
    int dst = ei[ne + e];
    float4 v = *reinterpret_cast<const float4*>(x + (long long)src * D + d0);
    float* o = out + (long long)dst * D + d0;
    atomicAdd(o + 0, v.x);
    atomicAdd(o + 1, v.y);
    atomicAdd(o + 2, v.z);
    atomicAdd(o + 3, v.w);
}

// ===========================================================================
// MLP: in-place row-tile GEMM  out[r] = act(in[r] @ W + b)
// ===========================================================================
template <bool RELU>
__global__ __launch_bounds__(MLP_THREADS, 1) void mlp_kernel(
    const float* __restrict__ in, const float* __restrict__ W,
    const float* __restrict__ b, float* __restrict__ outp, int nrows) {
    __shared__ float Wl[D][D];
    __shared__ float inl[TILE_ROWS][D + 4];

    const int tid = threadIdx.x;
    const int row0 = blockIdx.x * TILE_ROWS;

    for (int i = tid; i < D * D / 4; i += MLP_THREADS) {
        reinterpret_cast<float4*>(&Wl[0][0])[i] =
            reinterpret_cast<const float4*>(W)[i];
    }
    for (int i = tid; i < TILE_ROWS * (D / 4); i += MLP_THREADS) {
        int r = i >> 5;
        int k4 = i & 31;
        float4 v = make_float4(0.f, 0.f, 0.f, 0.f);
        if (row0 + r < nrows)
            v = *reinterpret_cast<const float4*>(in + (size_t)(row0 + r) * D + 4 * k4);
        *reinterpret_cast<float4*>(&inl[r][4 * k4]) = v;
    }
    __syncthreads();

    const int cg = tid & 31;
    const int rg = tid >> 5;
    const int c0 = cg * 4;
    const int r0 = rg * 4;

    float4 bv = *reinterpret_cast<const float4*>(b + c0);
    float acc[4][4];
#pragma unroll
    for (int i = 0; i < 4; ++i) {
        acc[i][0] = bv.x; acc[i][1] = bv.y; acc[i][2] = bv.z; acc[i][3] = bv.w;
    }

#pragma unroll 4
    for (int k4 = 0; k4 < 32; ++k4) {
        float4 w0 = *reinterpret_cast<const float4*>(&Wl[4 * k4 + 0][c0]);
        float4 w1 = *reinterpret_cast<const float4*>(&Wl[4 * k4 + 1][c0]);
        float4 w2 = *reinterpret_cast<const float4*>(&Wl[4 * k4 + 2][c0]);
        float4 w3 = *reinterpret_cast<const float4*>(&Wl[4 * k4 + 3][c0]);
#pragma unroll
        for (int i = 0; i < 4; ++i) {
            float4 a = *reinterpret_cast<const float4*>(&inl[r0 + i][4 * k4]);
            acc[i][0] += a.x * w0.x + a.y * w1.x + a.z * w2.x + a.w * w3.x;
            acc[i][1] += a.x * w0.y + a.y * w1.y + a.z * w2.y + a.w * w3.y;
            acc[i][2] += a.x * w0.z + a.y * w1.z + a.z * w2.z + a.w * w3.z;
            acc[i][3] += a.x * w0.w + a.y * w1.w + a.z * w2.w + a.w * w3.w;
        }
    }

#pragma unroll
    for (int i = 0; i < 4; ++i) {
        int r = row0 + r0 + i;
        if (r < nrows) {
            float4 o;
            if (RELU) {
                o.x = fmaxf(acc[i][0], 0.f); o.y = fmaxf(acc[i][1], 0.f);
                o.z = fmaxf(acc[i][2], 0.f); o.w = fmaxf(acc[i][3], 0.f);
            } else {
                o.x = acc[i][0]; o.y = acc[i][1]; o.z = acc[i][2]; o.w = acc[i][3];
            }
            *reinterpret_cast<float4*>(outp + (size_t)r * D + c0) = o;
        }
    }
}

extern "C" void kernel_launch(void* const* d_in, const int* in_sizes, int n_in,
                              void* d_out, int out_size, void* d_ws, size_t ws_size,
                              hipStream_t stream) {
    const float* x = (const float*)d_in[0];
    const int* ei = (const int*)d_in[1];
    const float* W1 = (const float*)d_in[2];
    const float* b1 = (const float*)d_in[3];
    const float* W2 = (const float*)d_in[4];
    const float* b2 = (const float*)d_in[5];
    float* out = (float*)d_out;

    const int nrows = in_sizes[0] / D;     // 100000 nodes
    const int ne = in_sizes[1] / 2;        // 3200000 edges
    const int nbkt = (nrows + BK_NODES - 1) / BK_NODES;

    size_t xh_bytes = (((size_t)nrows * D * sizeof(ushort_t)) + 15) & ~(size_t)15;
    size_t pairs_bytes = (size_t)ne * sizeof(int);
    size_t small_bytes = ((size_t)3 * nbkt + 1) * sizeof(int);
    size_t need_bf = xh_bytes + pairs_bytes + small_bytes;
    size_t need_fp = pairs_bytes + small_bytes;

    const int eblocks = (ne + 256 * EPB - 1) / (256 * EPB);

    if (nbkt <= MAX_BKT && ws_size >= need_fp) {
        const bool bf = (ws_size >= need_bf);
        char* wp = (char*)d_ws;
        ushort_t* xh = nullptr;
        if (bf) { xh = (ushort_t*)wp; wp += xh_bytes; }
        int* pairs = (int*)wp; wp += pairs_bytes;
        int* ghist = (int*)wp;
        int* cbase = ghist + nbkt;
        int* ccursor = cbase + (nbkt + 1);

        if (bf) {
            int n4 = nrows * (D / 4);
            cast_kernel<<<(n4 + 255) / 256, 256, 0, stream>>>(x, xh, n4);
        }
        zero_kernel<<<(nbkt + 255) / 256, 256, 0, stream>>>(ghist, nbkt);
        coarse_hist_kernel<<<eblocks, 256, 0, stream>>>(ei + ne, ghist, ne, nbkt);
        coarse_scan_kernel<<<1, SCAN_THREADS, 0, stream>>>(ghist, cbase, ccursor, nbkt);
        coarse_scatter_kernel<<<eblocks, 256, 0, stream>>>(ei, ccursor, pairs, ne, nbkt);

        if (bf)
            agg_pairs_kernel<0><<<nbkt, AGG_THREADS, 0, stream>>>(x, xh, pairs, cbase, out, nrows);
        else
            agg_pairs_kernel<1><<<nbkt, AGG_THREADS, 0, stream>>>(x, nullptr, pairs, cbase, out, nrows);
    } else {
        int n4 = nrows * (D / 4);
        init_kernel<<<(n4 + 255) / 256, 256, 0, stream>>>(x, out, n4);
        long long sthreads = (long long)ne * 32;
        scatter_kernel<<<(int)((sthreads + 255) / 256), 256, 0, stream>>>(x, ei, out, ne);
    }

    int mblocks = (nrows + TILE_ROWS - 1) / TILE_ROWS;
    mlp_kernel<true><<<mblocks, MLP_THREADS, 0, stream>>>(out, W1, b1, out, nrows);
    mlp_kernel<false><<<mblocks, MLP_THREADS, 0, stream>>>(out, W2, b2, out, nrows);
}

// Round 6
// 408.629 us; speedup vs baseline: 7.2345x; 7.2345x over previous
//
#include <hip/hip_runtime.h>

#define D 128
#define TILE_ROWS 64
#define MLP_THREADS 512
#define SCAN_THREADS 1024
#define BK_NODES 128     // dst-nodes per coarse bucket
#define MAX_BKT 1024
#define EPB 16           // edges per thread in coarse passes

typedef unsigned short ushort_t;
typedef unsigned int uint_t;

__device__ __forceinline__ ushort_t f2bf(float f) {
    uint_t u = __float_as_uint(f);
    u = u + 0x7FFFu + ((u >> 16) & 1u);   // round-to-nearest-even
    return (ushort_t)(u >> 16);
}

// ===========================================================================
// cast: x (fp32) -> xh (bf16), ushort4 stores
// ===========================================================================
__global__ void cast_kernel(const float* __restrict__ x, ushort_t* __restrict__ xh, int n4) {
    int i = blockIdx.x * blockDim.x + threadIdx.x;
    if (i < n4) {
        float4 v = reinterpret_cast<const float4*>(x)[i];
        ushort4 o;
        o.x = f2bf(v.x); o.y = f2bf(v.y); o.z = f2bf(v.z); o.w = f2bf(v.w);
        reinterpret_cast<ushort4*>(xh)[i] = o;
    }
}

// ===========================================================================
// Coarse CSR build (round-4 proven): zero -> hist -> scan -> scatter -> bucket
// pairs[] holds (src<<7)|(dst&127), grouped by coarse bucket (dst>>7).
// ===========================================================================
__global__ void zero_kernel(int* __restrict__ p, int n) {
    int i = blockIdx.x * blockDim.x + threadIdx.x;
    if (i < n) p[i] = 0;
}

__global__ void coarse_hist_kernel(const int* __restrict__ dsts,
                                   int* __restrict__ ghist, int ne, int nbkt) {
    __shared__ int h[MAX_BKT];
    for (int k = threadIdx.x; k < nbkt; k += blockDim.x) h[k] = 0;
    __syncthreads();
    int base = blockIdx.x * blockDim.x * EPB;
    for (int j = 0; j < EPB; ++j) {
        int e = base + j * blockDim.x + threadIdx.x;
        if (e < ne) atomicAdd(&h[dsts[e] >> 7], 1);
    }
    __syncthreads();
    for (int k = threadIdx.x; k < nbkt; k += blockDim.x)
        if (h[k]) atomicAdd(&ghist[k], h[k]);
}

__global__ __launch_bounds__(SCAN_THREADS) void coarse_scan_kernel(
    const int* __restrict__ ghist, int* __restrict__ cbase,
    int* __restrict__ ccursor, int* __restrict__ offsets,
    int nbkt, int nnodes, int ne) {
    __shared__ int sc[SCAN_THREADS];
    int t = threadIdx.x;
    int v = (t < nbkt) ? ghist[t] : 0;
    sc[t] = v;
    __syncthreads();
    for (int off = 1; off < SCAN_THREADS; off <<= 1) {
        int u = (t >= off) ? sc[t - off] : 0;
        __syncthreads();
        sc[t] += u;
        __syncthreads();
    }
    if (t < nbkt) { cbase[t] = sc[t] - v; ccursor[t] = sc[t] - v; }
    if (t == 0) { cbase[nbkt] = sc[SCAN_THREADS - 1]; offsets[nnodes] = ne; }
}

__global__ void coarse_scatter_kernel(const int* __restrict__ ei,
                                      int* __restrict__ ccursor,
                                      int* __restrict__ pairs, int ne, int nbkt) {
    __shared__ int h[MAX_BKT];
    __shared__ int cur[MAX_BKT];
    for (int k = threadIdx.x; k < nbkt; k += blockDim.x) h[k] = 0;
    __syncthreads();
    int base = blockIdx.x * blockDim.x * EPB;
    for (int j = 0; j < EPB; ++j) {
        int e = base + j * blockDim.x + threadIdx.x;
        if (e < ne) atomicAdd(&h[ei[ne + e] >> 7], 1);
    }
    __syncthreads();
    for (int k = threadIdx.x; k < nbkt; k += blockDim.x)
        cur[k] = h[k] ? atomicAdd(&ccursor[k], h[k]) : 0;
    __syncthreads();
    for (int j = 0; j < EPB; ++j) {
        int e = base + j * blockDim.x + threadIdx.x;
        if (e < ne) {
            int dst = ei[ne + e];
            int src = ei[e];
            int k = dst >> 7;
            int pos = atomicAdd(&cur[k], 1);
            pairs[pos] = (src << 7) | (dst & (BK_NODES - 1));
        }
    }
}

__global__ void bucket_csr_kernel(const int* __restrict__ pairs,
                                  const int* __restrict__ cbase,
                                  int* __restrict__ offsets,
                                  int* __restrict__ sorted_src,
                                  int nnodes) {
    __shared__ int h[BK_NODES];
    __shared__ int ex[BK_NODES];
    __shared__ int cur[BK_NODES];
    int b = blockIdx.x;
    int t = threadIdx.x;
    int rbeg = cbase[b], rend = cbase[b + 1];
    if (t < BK_NODES) h[t] = 0;
    __syncthreads();
    for (int i = rbeg + t; i < rend; i += blockDim.x)
        atomicAdd(&h[pairs[i] & (BK_NODES - 1)], 1);
    __syncthreads();
    if (t < BK_NODES) ex[t] = h[t];
    __syncthreads();
    for (int off = 1; off < BK_NODES; off <<= 1) {
        int u = (t >= off && t < BK_NODES) ? ex[t - off] : 0;
        __syncthreads();
        if (t < BK_NODES) ex[t] += u;
        __syncthreads();
    }
    if (t < BK_NODES) {
        int e = ex[t] - h[t];          // exclusive within bucket
        cur[t] = rbeg + e;
        int node = b * BK_NODES + t;
        if (node < nnodes) offsets[node] = rbeg + e;
    }
    __syncthreads();
    for (int i = rbeg + t; i < rend; i += blockDim.x) {
        int p = pairs[i];
        int pos = atomicAdd(&cur[p & (BK_NODES - 1)], 1);
        sorted_src[pos] = p >> 7;
    }
}

// ===========================================================================
// agg: one wave per node, unroll x8 (8 independent row-gathers in flight).
// MODE 0: gather bf16 (one uint = 2 bf16 per lane, 256B/wave-row).
// MODE 1: gather fp32 (float2 per lane, 512B/wave-row).
// Self-term from fp32 x; fp32 accumulate; fp32 output.
// ===========================================================================
template <int MODE>
__global__ void agg_kernel(const float* __restrict__ x,
                           const ushort_t* __restrict__ xh,
                           const int* __restrict__ sorted_src,
                           const int* __restrict__ offsets,
                           float* __restrict__ out, int nnodes) {
    int gid = blockIdx.x * blockDim.x + threadIdx.x;
    int node = gid >> 6;
    if (node >= nnodes) return;
    int lane = threadIdx.x & 63;
    int beg = offsets[node];
    int end = offsets[node + 1];
    float2 a = reinterpret_cast<const float2*>(x)[(size_t)node * 64 + lane];
    float sx = a.x, sy = a.y;
    int i = beg;
    if (MODE == 0) {
        const uint_t* xp = reinterpret_cast<const uint_t*>(xh);  // 64 uints/row
        for (; i + 8 <= end; i += 8) {
            int s0 = sorted_src[i + 0], s1 = sorted_src[i + 1];
            int s2 = sorted_src[i + 2], s3 = sorted_src[i + 3];
            int s4 = sorted_src[i + 4], s5 = sorted_src[i + 5];
            int s6 = sorted_src[i + 6], s7 = sorted_src[i + 7];
            uint_t u0 = xp[(size_t)s0 * 64 + lane];
            uint_t u1 = xp[(size_t)s1 * 64 + lane];
            uint_t u2 = xp[(size_t)s2 * 64 + lane];
            uint_t u3 = xp[(size_t)s3 * 64 + lane];
            uint_t u4 = xp[(size_t)s4 * 64 + lane];
            uint_t u5 = xp[(size_t)s5 * 64 + lane];
            uint_t u6 = xp[(size_t)s6 * 64 + lane];
            uint_t u7 = xp[(size_t)s7 * 64 + lane];
            sx += __uint_as_float(u0 << 16) + __uint_as_float(u1 << 16) +
                  __uint_as_float(u2 << 16) + __uint_as_float(u3 << 16) +
                  __uint_as_float(u4 << 16) + __uint_as_float(u5 << 16) +
                  __uint_as_float(u6 << 16) + __uint_as_float(u7 << 16);
            sy += __uint_as_float(u0 & 0xffff0000u) + __uint_as_float(u1 & 0xffff0000u) +
                  __uint_as_float(u2 & 0xffff0000u) + __uint_as_float(u3 & 0xffff0000u) +
                  __uint_as_float(u4 & 0xffff0000u) + __uint_as_float(u5 & 0xffff0000u) +
                  __uint_as_float(u6 & 0xffff0000u) + __uint_as_float(u7 & 0xffff0000u);
        }
        for (; i < end; ++i) {
            uint_t u = xp[(size_t)sorted_src[i] * 64 + lane];
            sx += __uint_as_float(u << 16);
            sy += __uint_as_float(u & 0xffff0000u);
        }
    } else {
        const float2* xp = reinterpret_cast<const float2*>(x);
        for (; i + 8 <= end; i += 8) {
            int s0 = sorted_src[i + 0], s1 = sorted_src[i + 1];
            int s2 = sorted_src[i + 2], s3 = sorted_src[i + 3];
            int s4 = sorted_src[i + 4], s5 = sorted_src[i + 5];
            int s6 = sorted_src[i + 6], s7 = sorted_src[i + 7];
            float2 v0 = xp[(size_t)s0 * 64 + lane];
            float2 v1 = xp[(size_t)s1 * 64 + lane];
            float2 v2 = xp[(size_t)s2 * 64 + lane];
            float2 v3 = xp[(size_t)s3 * 64 + lane];
            float2 v4 = xp[(size_t)s4 * 64 + lane];
            float2 v5 = xp[(size_t)s5 * 64 + lane];
            float2 v6 = xp[(size_t)s6 * 64 + lane];
            float2 v7 = xp[(size_t)s7 * 64 + lane];
            sx += ((v0.x + v1.x) + (v2.x + v3.x)) + ((v4.x + v5.x) + (v6.x + v7.x));
            sy += ((v0.y + v1.y) + (v2.y + v3.y)) + ((v4.y + v5.y) + (v6.y + v7.y));
        }
        for (; i < end; ++i) {
            float2 v = xp[(size_t)sorted_src[i] * 64 + lane];
            sx += v.x;
            sy += v.y;
        }
    }
    float2 o;
    o.x = sx;
    o.y = sy;
    reinterpret_cast<float2*>(out)[(size_t)node * 64 + lane] = o;
}

// ===========================================================================
// Fallback: init + fp32 atomic scatter
// ===========================================================================
__global__ void init_kernel(const float* __restrict__ x, float* __restrict__ out, int n4) {
    int i = blockIdx.x * blockDim.x + threadIdx.x;
    if (i < n4) {
        reinterpret_cast<float4*>(out)[i] = reinterpret_cast<const float4*>(x)[i];
    }
}

__global__ void scatter_kernel(const float* __restrict__ x,
                               const int* __restrict__ ei,
                               float* __restrict__ out, int ne) {
    long long gid = (long long)blockIdx.x * blockDim.x + threadIdx.x;
    int e = (int)(gid >> 5);
    if (e >= ne) return;
    int d0 = ((int)gid & 31) * 4;
    int src = ei[e];
    int dst = ei[ne + e];
    float4 v = *reinterpret_cast<const float4*>(x + (long long)src * D + d0);
    float* o = out + (long long)dst * D + d0;
    atomicAdd(o + 0, v.x);
    atomicAdd(o + 1, v.y);
    atomicAdd(o + 2, v.z);
    atomicAdd(o + 3, v.w);
}

// ===========================================================================
// MLP: in-place row-tile GEMM  out[r] = act(in[r] @ W + b)
// ===========================================================================
template <bool RELU>
__global__ __launch_bounds__(MLP_THREADS, 1) void mlp_kernel(
    const float* __restrict__ in, const float* __restrict__ W,
    const float* __restrict__ b, float* __restrict__ outp, int nrows) {
    __shared__ float Wl[D][D];
    __shared__ float inl[TILE_ROWS][D + 4];

    const int tid = threadIdx.x;
    const int row0 = blockIdx.x * TILE_ROWS;

    for (int i = tid; i < D * D / 4; i += MLP_THREADS) {
        reinterpret_cast<float4*>(&Wl[0][0])[i] =
            reinterpret_cast<const float4*>(W)[i];
    }
    for (int i = tid; i < TILE_ROWS * (D / 4); i += MLP_THREADS) {
        int r = i >> 5;
        int k4 = i & 31;
        float4 v = make_float4(0.f, 0.f, 0.f, 0.f);
        if (row0 + r < nrows)
            v = *reinterpret_cast<const float4*>(in + (size_t)(row0 + r) * D + 4 * k4);
        *reinterpret_cast<float4*>(&inl[r][4 * k4]) = v;
    }
    __syncthreads();

    const int cg = tid & 31;
    const int rg = tid >> 5;
    const int c0 = cg * 4;
    const int r0 = rg * 4;

    float4 bv = *reinterpret_cast<const float4*>(b + c0);
    float acc[4][4];
#pragma unroll
    for (int i = 0; i < 4; ++i) {
        acc[i][0] = bv.x; acc[i][1] = bv.y; acc[i][2] = bv.z; acc[i][3] = bv.w;
    }

#pragma unroll 4
    for (int k4 = 0; k4 < 32; ++k4) {
        float4 w0 = *reinterpret_cast<const float4*>(&Wl[4 * k4 + 0][c0]);
        float4 w1 = *reinterpret_cast<const float4*>(&Wl[4 * k4 + 1][c0]);
        float4 w2 = *reinterpret_cast<const float4*>(&Wl[4 * k4 + 2][c0]);
        float4 w3 = *reinterpret_cast<const float4*>(&Wl[4 * k4 + 3][c0]);
#pragma unroll
        for (int i = 0; i < 4; ++i) {
            float4 a = *reinterpret_cast<const float4*>(&inl[r0 + i][4 * k4]);
            acc[i][0] += a.x * w0.x + a.y * w1.x + a.z * w2.x + a.w * w3.x;
            acc[i][1] += a.x * w0.y + a.y * w1.y + a.z * w2.y + a.w * w3.y;
            acc[i][2] += a.x * w0.z + a.y * w1.z + a.z * w2.z + a.w * w3.z;
            acc[i][3] += a.x * w0.w + a.y * w1.w + a.z * w2.w + a.w * w3.w;
        }
    }

#pragma unroll
    for (int i = 0; i < 4; ++i) {
        int r = row0 + r0 + i;
        if (r < nrows) {
            float4 o;
            if (RELU) {
                o.x = fmaxf(acc[i][0], 0.f); o.y = fmaxf(acc[i][1], 0.f);
                o.z = fmaxf(acc[i][2], 0.f); o.w = fmaxf(acc[i][3], 0.f);
            } else {
                o.x = acc[i][0]; o.y = acc[i][1]; o.z = acc[i][2]; o.w = acc[i][3];
            }
            *reinterpret_cast<float4*>(outp + (size_t)r * D + c0) = o;
        }
    }
}

extern "C" void kernel_launch(void* const* d_in, const int* in_sizes, int n_in,
                              void* d_out, int out_size, void* d_ws, size_t ws_size,
                              hipStream_t stream) {
    const float* x = (const float*)d_in[0];
    const int* ei = (const int*)d_in[1];
    const float* W1 = (const float*)d_in[2];
    const float* b1 = (const float*)d_in[3];
    const float* W2 = (const float*)d_in[4];
    const float* b2 = (const float*)d_in[5];
    float* out = (float*)d_out;

    const int nrows = in_sizes[0] / D;     // 100000 nodes
    const int ne = in_sizes[1] / 2;        // 3200000 edges
    const int nbkt = (nrows + BK_NODES - 1) / BK_NODES;

    // ws layout: [xh (tier A only)] | offsets[nrows+1] | sorted_src[ne]
    //            | pairs[ne] | ghist[nbkt] | cbase[nbkt+1] | ccursor[nbkt]
    size_t xh_bytes = (((size_t)nrows * D * sizeof(ushort_t)) + 15) & ~(size_t)15;
    size_t csr_bytes = ((size_t)(nrows + 1) + 2 * (size_t)ne + 3 * (size_t)nbkt + 1) * sizeof(int);
    size_t need_bf = xh_bytes + csr_bytes;
    size_t need_fp = csr_bytes;

    const int eblocks = (ne + 256 * EPB - 1) / (256 * EPB);

    if (nbkt <= MAX_BKT && ws_size >= need_fp) {
        const bool bf = (ws_size >= need_bf);
        char* wp = (char*)d_ws;
        ushort_t* xh = nullptr;
        if (bf) { xh = (ushort_t*)wp; wp += xh_bytes; }
        int* offsets = (int*)wp;
        int* sorted_src = offsets + (nrows + 1);
        int* pairs = sorted_src + ne;
        int* ghist = pairs + ne;
        int* cbase = ghist + nbkt;
        int* ccursor = cbase + (nbkt + 1);

        if (bf) {
            int n4 = nrows * (D / 4);
            cast_kernel<<<(n4 + 255) / 256, 256, 0, stream>>>(x, xh, n4);
        }
        zero_kernel<<<(nbkt + 255) / 256, 256, 0, stream>>>(ghist, nbkt);
        coarse_hist_kernel<<<eblocks, 256, 0, stream>>>(ei + ne, ghist, ne, nbkt);
        coarse_scan_kernel<<<1, SCAN_THREADS, 0, stream>>>(ghist, cbase, ccursor,
                                                           offsets, nbkt, nrows, ne);
        coarse_scatter_kernel<<<eblocks, 256, 0, stream>>>(ei, ccursor, pairs, ne, nbkt);
        bucket_csr_kernel<<<nbkt, 256, 0, stream>>>(pairs, cbase, offsets, sorted_src, nrows);

        long long athreads = (long long)nrows * 64;
        int ablocks = (int)((athreads + 255) / 256);
        if (bf)
            agg_kernel<0><<<ablocks, 256, 0, stream>>>(x, xh, sorted_src, offsets, out, nrows);
        else
            agg_kernel<1><<<ablocks, 256, 0, stream>>>(x, nullptr, sorted_src, offsets, out, nrows);
    } else {
        int n4 = nrows * (D / 4);
        init_kernel<<<(n4 + 255) / 256, 256, 0, stream>>>(x, out, n4);
        long long sthreads = (long long)ne * 32;
        scatter_kernel<<<(int)((sthreads + 255) / 256), 256, 0, stream>>>(x, ei, out, ne);
    }

    int mblocks = (nrows + TILE_ROWS - 1) / TILE_ROWS;
    mlp_kernel<true><<<mblocks, MLP_THREADS, 0, stream>>>(out, W1, b1, out, nrows);
    mlp_kernel<false><<<mblocks, MLP_THREADS, 0, stream>>>(out, W2, b2, out, nrows);
}

// Round 7
// 294.193 us; speedup vs baseline: 10.0486x; 1.3890x over previous
//
#include <hip/hip_runtime.h>

#define D 128
#define TILE_ROWS 64
#define MLP_THREADS 512
#define SCAN_THREADS 1024
#define BK_NODES 128     // dst-nodes per coarse bucket
#define MAX_BKT 1024
#define EPB 16           // edges per thread in coarse passes
#define FMLP_THREADS 512
#define MLP_BM 128
#define HSTR 136         // padded LDS row stride (bf16 elems): 272B -> 2-way bank alias (free)

typedef unsigned short ushort_t;
typedef unsigned int uint_t;
typedef __attribute__((ext_vector_type(8))) short short8v;   // 8 bf16 (4 VGPR)
typedef __attribute__((ext_vector_type(4))) float f32x4;

__device__ __forceinline__ ushort_t f2bf(float f) {
    uint_t u = __float_as_uint(f);
    u = u + 0x7FFFu + ((u >> 16) & 1u);   // round-to-nearest-even
    return (ushort_t)(u >> 16);
}

// ===========================================================================
// cast: x (fp32) -> xh (bf16), ushort4 stores
// ===========================================================================
__global__ void cast_kernel(const float* __restrict__ x, ushort_t* __restrict__ xh, int n4) {
    int i = blockIdx.x * blockDim.x + threadIdx.x;
    if (i < n4) {
        float4 v = reinterpret_cast<const float4*>(x)[i];
        ushort4 o;
        o.x = f2bf(v.x); o.y = f2bf(v.y); o.z = f2bf(v.z); o.w = f2bf(v.w);
        reinterpret_cast<ushort4*>(xh)[i] = o;
    }
}

// ===========================================================================
// wprep: W (fp32 [k][c]) -> Wt (bf16 [c][HSTR]) for MFMA B-fragments
// ===========================================================================
__global__ void wprep_kernel(const float* __restrict__ W1, const float* __restrict__ W2,
                             ushort_t* __restrict__ w1t, ushort_t* __restrict__ w2t) {
    int i = blockIdx.x * blockDim.x + threadIdx.x;
    if (i < D * D) {
        int c = i & 127, k = i >> 7;
        w1t[(size_t)c * HSTR + k] = f2bf(W1[(size_t)k * D + c]);
        w2t[(size_t)c * HSTR + k] = f2bf(W2[(size_t)k * D + c]);
    }
}

// ===========================================================================
// Coarse CSR build (round-4 proven): zero -> hist -> scan -> scatter -> bucket
// pairs[] holds (src<<7)|(dst&127), grouped by coarse bucket (dst>>7).
// ===========================================================================
__global__ void zero_kernel(int* __restrict__ p, int n) {
    int i = blockIdx.x * blockDim.x + threadIdx.x;
    if (i < n) p[i] = 0;
}

__global__ void coarse_hist_kernel(const int* __restrict__ dsts,
                                   int* __restrict__ ghist, int ne, int nbkt) {
    __shared__ int h[MAX_BKT];
    for (int k = threadIdx.x; k < nbkt; k += blockDim.x) h[k] = 0;
    __syncthreads();
    int base = blockIdx.x * blockDim.x * EPB;
    for (int j = 0; j < EPB; ++j) {
        int e = base + j * blockDim.x + threadIdx.x;
        if (e < ne) atomicAdd(&h[dsts[e] >> 7], 1);
    }
    __syncthreads();
    for (int k = threadIdx.x; k < nbkt; k += blockDim.x)
        if (h[k]) atomicAdd(&ghist[k], h[k]);
}

__global__ __launch_bounds__(SCAN_THREADS) void coarse_scan_kernel(
    const int* __restrict__ ghist, int* __restrict__ cbase,
    int* __restrict__ ccursor, int* __restrict__ offsets,
    int nbkt, int nnodes, int ne) {
    __shared__ int sc[SCAN_THREADS];
    int t = threadIdx.x;
    int v = (t < nbkt) ? ghist[t] : 0;
    sc[t] = v;
    __syncthreads();
    for (int off = 1; off < SCAN_THREADS; off <<= 1) {
        int u = (t >= off) ? sc[t - off] : 0;
        __syncthreads();
        sc[t] += u;
        __syncthreads();
    }
    if (t < nbkt) { cbase[t] = sc[t] - v; ccursor[t] = sc[t] - v; }
    if (t == 0) { cbase[nbkt] = sc[SCAN_THREADS - 1]; offsets[nnodes] = ne; }
}

__global__ void coarse_scatter_kernel(const int* __restrict__ ei,
                                      int* __restrict__ ccursor,
                                      int* __restrict__ pairs, int ne, int nbkt) {
    __shared__ int h[MAX_BKT];
    __shared__ int cur[MAX_BKT];
    for (int k = threadIdx.x; k < nbkt; k += blockDim.x) h[k] = 0;
    __syncthreads();
    int base = blockIdx.x * blockDim.x * EPB;
    for (int j = 0; j < EPB; ++j) {
        int e = base + j * blockDim.x + threadIdx.x;
        if (e < ne) atomicAdd(&h[ei[ne + e] >> 7], 1);
    }
    __syncthreads();
    for (int k = threadIdx.x; k < nbkt; k += blockDim.x)
        cur[k] = h[k] ? atomicAdd(&ccursor[k], h[k]) : 0;
    __syncthreads();
    for (int j = 0; j < EPB; ++j) {
        int e = base + j * blockDim.x + threadIdx.x;
        if (e < ne) {
            int dst = ei[ne + e];
            int src = ei[e];
            int k = dst >> 7;
            int pos = atomicAdd(&cur[k], 1);
            pairs[pos] = (src << 7) | (dst & (BK_NODES - 1));
        }
    }
}

__global__ void bucket_csr_kernel(const int* __restrict__ pairs,
                                  const int* __restrict__ cbase,
                                  int* __restrict__ offsets,
                                  int* __restrict__ sorted_src,
                                  int nnodes) {
    __shared__ int h[BK_NODES];
    __shared__ int ex[BK_NODES];
    __shared__ int cur[BK_NODES];
    int b = blockIdx.x;
    int t = threadIdx.x;
    int rbeg = cbase[b], rend = cbase[b + 1];
    if (t < BK_NODES) h[t] = 0;
    __syncthreads();
    for (int i = rbeg + t; i < rend; i += blockDim.x)
        atomicAdd(&h[pairs[i] & (BK_NODES - 1)], 1);
    __syncthreads();
    if (t < BK_NODES) ex[t] = h[t];
    __syncthreads();
    for (int off = 1; off < BK_NODES; off <<= 1) {
        int u = (t >= off && t < BK_NODES) ? ex[t - off] : 0;
        __syncthreads();
        if (t < BK_NODES) ex[t] += u;
        __syncthreads();
    }
    if (t < BK_NODES) {
        int e = ex[t] - h[t];          // exclusive within bucket
        cur[t] = rbeg + e;
        int node = b * BK_NODES + t;
        if (node < nnodes) offsets[node] = rbeg + e;
    }
    __syncthreads();
    for (int i = rbeg + t; i < rend; i += blockDim.x) {
        int p = pairs[i];
        int pos = atomicAdd(&cur[p & (BK_NODES - 1)], 1);
        sorted_src[pos] = p >> 7;
    }
}

// ===========================================================================
// agg: one wave per node, unroll x8. MODE 0: bf16 gather; MODE 1: fp32.
// ===========================================================================
template <int MODE>
__global__ void agg_kernel(const float* __restrict__ x,
                           const ushort_t* __restrict__ xh,
                           const int* __restrict__ sorted_src,
                           const int* __restrict__ offsets,
                           float* __restrict__ out, int nnodes) {
    int gid = blockIdx.x * blockDim.x + threadIdx.x;
    int node = gid >> 6;
    if (node >= nnodes) return;
    int lane = threadIdx.x & 63;
    int beg = offsets[node];
    int end = offsets[node + 1];
    float2 a = reinterpret_cast<const float2*>(x)[(size_t)node * 64 + lane];
    float sx = a.x, sy = a.y;
    int i = beg;
    if (MODE == 0) {
        const uint_t* xp = reinterpret_cast<const uint_t*>(xh);  // 64 uints/row
        for (; i + 8 <= end; i += 8) {
            int s0 = sorted_src[i + 0], s1 = sorted_src[i + 1];
            int s2 = sorted_src[i + 2], s3 = sorted_src[i + 3];
            int s4 = sorted_src[i + 4], s5 = sorted_src[i + 5];
            int s6 = sorted_src[i + 6], s7 = sorted_src[i + 7];
            uint_t u0 = xp[(size_t)s0 * 64 + lane];
            uint_t u1 = xp[(size_t)s1 * 64 + lane];
            uint_t u2 = xp[(size_t)s2 * 64 + lane];
            uint_t u3 = xp[(size_t)s3 * 64 + lane];
            uint_t u4 = xp[(size_t)s4 * 64 + lane];
            uint_t u5 = xp[(size_t)s5 * 64 + lane];
            uint_t u6 = xp[(size_t)s6 * 64 + lane];
            uint_t u7 = xp[(size_t)s7 * 64 + lane];
            sx += __uint_as_float(u0 << 16) + __uint_as_float(u1 << 16) +
                  __uint_as_float(u2 << 16) + __uint_as_float(u3 << 16) +
                  __uint_as_float(u4 << 16) + __uint_as_float(u5 << 16) +
                  __uint_as_float(u6 << 16) + __uint_as_float(u7 << 16);
            sy += __uint_as_float(u0 & 0xffff0000u) + __uint_as_float(u1 & 0xffff0000u) +
                  __uint_as_float(u2 & 0xffff0000u) + __uint_as_float(u3 & 0xffff0000u) +
                  __uint_as_float(u4 & 0xffff0000u) + __uint_as_float(u5 & 0xffff0000u) +
                  __uint_as_float(u6 & 0xffff0000u) + __uint_as_float(u7 & 0xffff0000u);
        }
        for (; i < end; ++i) {
            uint_t u = xp[(size_t)sorted_src[i] * 64 + lane];
            sx += __uint_as_float(u << 16);
            sy += __uint_as_float(u & 0xffff0000u);
        }
    } else {
        const float2* xp = reinterpret_cast<const float2*>(x);
        for (; i + 8 <= end; i += 8) {
            int s0 = sorted_src[i + 0], s1 = sorted_src[i + 1];
            int s2 = sorted_src[i + 2], s3 = sorted_src[i + 3];
            int s4 = sorted_src[i + 4], s5 = sorted_src[i + 5];
            int s6 = sorted_src[i + 6], s7 = sorted_src[i + 7];
            float2 v0 = xp[(size_t)s0 * 64 + lane];
            float2 v1 = xp[(size_t)s1 * 64 + lane];
            float2 v2 = xp[(size_t)s2 * 64 + lane];
            float2 v3 = xp[(size_t)s3 * 64 + lane];
            float2 v4 = xp[(size_t)s4 * 64 + lane];
            float2 v5 = xp[(size_t)s5 * 64 + lane];
            float2 v6 = xp[(size_t)s6 * 64 + lane];
            float2 v7 = xp[(size_t)s7 * 64 + lane];
            sx += ((v0.x + v1.x) + (v2.x + v3.x)) + ((v4.x + v5.x) + (v6.x + v7.x));
            sy += ((v0.y + v1.y) + (v2.y + v3.y)) + ((v4.y + v5.y) + (v6.y + v7.y));
        }
        for (; i < end; ++i) {
            float2 v = xp[(size_t)sorted_src[i] * 64 + lane];
            sx += v.x;
            sy += v.y;
        }
    }
    float2 o;
    o.x = sx;
    o.y = sy;
    reinterpret_cast<float2*>(out)[(size_t)node * 64 + lane] = o;
}

// ===========================================================================
// fused_mlp: out = relu(h@W1+b1)@W2+b2, bf16 MFMA, in-place on d_out.
// 512 threads = 8 waves, 128 rows/block; each wave owns 16 rows.
// LDS: h/h1 tile [128][HSTR] + W1t + W2t  (104.4 KB, 1 block/CU).
// ===========================================================================
__global__ __launch_bounds__(FMLP_THREADS, 1) void fused_mlp_kernel(
    const float* __restrict__ h, const ushort_t* __restrict__ w1t,
    const ushort_t* __restrict__ w2t, const float* __restrict__ b1,
    const float* __restrict__ b2, float* __restrict__ outp, int nrows) {
    __shared__ ushort_t sh[MLP_BM * HSTR];
    __shared__ ushort_t sw1[D * HSTR];
    __shared__ ushort_t sw2[D * HSTR];
    const int tid = threadIdx.x;
    const int row0 = blockIdx.x * MLP_BM;

    // stage W1t/W2t (pre-transposed bf16, same layout) - 2176 uint4 each
    {
        const uint4* s1 = reinterpret_cast<const uint4*>(w1t);
        const uint4* s2 = reinterpret_cast<const uint4*>(w2t);
        uint4* d1 = reinterpret_cast<uint4*>(sw1);
        uint4* d2 = reinterpret_cast<uint4*>(sw2);
        for (int i = tid; i < D * HSTR / 8; i += FMLP_THREADS) { d1[i] = s1[i]; d2[i] = s2[i]; }
    }
    // stage h tile: fp32 global (d_out) -> bf16 LDS
    for (int i = tid; i < MLP_BM * 32; i += FMLP_THREADS) {
        int r = i >> 5, c4 = i & 31;
        float4 v = make_float4(0.f, 0.f, 0.f, 0.f);
        if (row0 + r < nrows)
            v = reinterpret_cast<const float4*>(h + (size_t)(row0 + r) * D)[c4];
        ushort4 o;
        o.x = f2bf(v.x); o.y = f2bf(v.y); o.z = f2bf(v.z); o.w = f2bf(v.w);
        *reinterpret_cast<ushort4*>(&sh[r * HSTR + c4 * 4]) = o;
    }
    __syncthreads();

    const int w = tid >> 6, l = tid & 63;
    const int lr = l & 15, lg = l >> 4;
    const int rowb = w * 16;

    // ---- layer 1: h1 = relu(h @ W1 + b1), written back over own h rows ----
    short8v A[4];
#pragma unroll
    for (int kk = 0; kk < 4; ++kk)
        A[kk] = *reinterpret_cast<const short8v*>(&sh[(rowb + lr) * HSTR + kk * 32 + lg * 8]);
#pragma unroll
    for (int n = 0; n < 8; ++n) {
        float bv = b1[n * 16 + lr];
        f32x4 acc = {bv, bv, bv, bv};
#pragma unroll
        for (int kk = 0; kk < 4; ++kk) {
            short8v B = *reinterpret_cast<const short8v*>(&sw1[(n * 16 + lr) * HSTR + kk * 32 + lg * 8]);
            acc = __builtin_amdgcn_mfma_f32_16x16x32_bf16(A[kk], B, acc, 0, 0, 0);
        }
#pragma unroll
        for (int r = 0; r < 4; ++r) {
            // C/D: col = lane&15 (+16n), row = (lane>>4)*4 + r   [m89-verified]
            float v = fmaxf(acc[r], 0.f);
            sh[(rowb + lg * 4 + r) * HSTR + n * 16 + lr] = f2bf(v);
        }
    }

    // ---- layer 2: out = h1 @ W2 + b2 (wave-local rows; no block barrier) ----
    short8v A2[4];
#pragma unroll
    for (int kk = 0; kk < 4; ++kk)
        A2[kk] = *reinterpret_cast<const short8v*>(&sh[(rowb + lr) * HSTR + kk * 32 + lg * 8]);
#pragma unroll
    for (int n = 0; n < 8; ++n) {
        float bv = b2[n * 16 + lr];
        f32x4 acc = {bv, bv, bv, bv};
#pragma unroll
        for (int kk = 0; kk < 4; ++kk) {
            short8v B = *reinterpret_cast<const short8v*>(&sw2[(n * 16 + lr) * HSTR + kk * 32 + lg * 8]);
            acc = __builtin_amdgcn_mfma_f32_16x16x32_bf16(A2[kk], B, acc, 0, 0, 0);
        }
#pragma unroll
        for (int r = 0; r < 4; ++r) {
            int grow = row0 + rowb + lg * 4 + r;
            if (grow < nrows)
                outp[(size_t)grow * D + n * 16 + lr] = acc[r];
        }
    }
}

// ===========================================================================
// Fallback: init + fp32 atomic scatter
// ===========================================================================
__global__ void init_kernel(const float* __restrict__ x, float* __restrict__ out, int n4) {
    int i = blockIdx.x * blockDim.x + threadIdx.x;
    if (i < n4) {
        reinterpret_cast<float4*>(out)[i] = reinterpret_cast<const float4*>(x)[i];
    }
}

__global__ void scatter_kernel(const float* __restrict__ x,
                               const int* __restrict__ ei,
                               float* __restrict__ out, int ne) {
    long long gid = (long long)blockIdx.x * blockDim.x + threadIdx.x;
    int e = (int)(gid >> 5);
    if (e >= ne) return;
    int d0 = ((int)gid & 31) * 4;
    int src = ei[e];
    int dst = ei[ne + e];
    float4 v = *reinterpret_cast<const float4*>(x + (long long)src * D + d0);
    float* o = out + (long long)dst * D + d0;
    atomicAdd(o + 0, v.x);
    atomicAdd(o + 1, v.y);
    atomicAdd(o + 2, v.z);
    atomicAdd(o + 3, v.w);
}

// ===========================================================================
// Fallback MLP: fp32 in-place row-tile GEMM
// ===========================================================================
template <bool RELU>
__global__ __launch_bounds__(MLP_THREADS, 1) void mlp_kernel(
    const float* __restrict__ in, const float* __restrict__ W,
    const float* __restrict__ b, float* __restrict__ outp, int nrows) {
    __shared__ float Wl[D][D];
    __shared__ float inl[TILE_ROWS][D + 4];

    const int tid = threadIdx.x;
    const int row0 = blockIdx.x * TILE_ROWS;

    for (int i = tid; i < D * D / 4; i += MLP_THREADS) {
        reinterpret_cast<float4*>(&Wl[0][0])[i] =
            reinterpret_cast<const float4*>(W)[i];
    }
    for (int i = tid; i < TILE_ROWS * (D / 4); i += MLP_THREADS) {
        int r = i >> 5;
        int k4 = i & 31;
        float4 v = make_float4(0.f, 0.f, 0.f, 0.f);
        if (row0 + r < nrows)
            v = *reinterpret_cast<const float4*>(in + (size_t)(row0 + r) * D + 4 * k4);
        *reinterpret_cast<float4*>(&inl[r][4 * k4]) = v;
    }
    __syncthreads();

    const int cg = tid & 31;
    const int rg = tid >> 5;
    const int c0 = cg * 4;
    const int r0 = rg * 4;

    float4 bv = *reinterpret_cast<const float4*>(b + c0);
    float acc[4][4];
#pragma unroll
    for (int i = 0; i < 4; ++i) {
        acc[i][0] = bv.x; acc[i][1] = bv.y; acc[i][2] = bv.z; acc[i][3] = bv.w;
    }

#pragma unroll 4
    for (int k4 = 0; k4 < 32; ++k4) {
        float4 w0 = *reinterpret_cast<const float4*>(&Wl[4 * k4 + 0][c0]);
        float4 w1 = *reinterpret_cast<const float4*>(&Wl[4 * k4 + 1][c0]);
        float4 w2 = *reinterpret_cast<const float4*>(&Wl[4 * k4 + 2][c0]);
        float4 w3 = *reinterpret_cast<const float4*>(&Wl[4 * k4 + 3][c0]);
#pragma unroll
        for (int i = 0; i < 4; ++i) {
            float4 a = *reinterpret_cast<const float4*>(&inl[r0 + i][4 * k4]);
            acc[i][0] += a.x * w0.x + a.y * w1.x + a.z * w2.x + a.w * w3.x;
            acc[i][1] += a.x * w0.y + a.y * w1.y + a.z * w2.y + a.w * w3.y;
            acc[i][2] += a.x * w0.z + a.y * w1.z + a.z * w2.z + a.w * w3.z;
            acc[i][3] += a.x * w0.w + a.y * w1.w + a.z * w2.w + a.w * w3.w;
        }
    }

#pragma unroll
    for (int i = 0; i < 4; ++i) {
        int r = row0 + r0 + i;
        if (r < nrows) {
            float4 o;
            if (RELU) {
                o.x = fmaxf(acc[i][0], 0.f); o.y = fmaxf(acc[i][1], 0.f);
                o.z = fmaxf(acc[i][2], 0.f); o.w = fmaxf(acc[i][3], 0.f);
            } else {
                o.x = acc[i][0]; o.y = acc[i][1]; o.z = acc[i][2]; o.w = acc[i][3];
            }
            *reinterpret_cast<float4*>(outp + (size_t)r * D + c0) = o;
        }
    }
}

extern "C" void kernel_launch(void* const* d_in, const int* in_sizes, int n_in,
                              void* d_out, int out_size, void* d_ws, size_t ws_size,
                              hipStream_t stream) {
    const float* x = (const float*)d_in[0];
    const int* ei = (const int*)d_in[1];
    const float* W1 = (const float*)d_in[2];
    const float* b1 = (const float*)d_in[3];
    const float* W2 = (const float*)d_in[4];
    const float* b2 = (const float*)d_in[5];
    float* out = (float*)d_out;

    const int nrows = in_sizes[0] / D;     // 100000 nodes
    const int ne = in_sizes[1] / 2;        // 3200000 edges
    const int nbkt = (nrows + BK_NODES - 1) / BK_NODES;

    // ws layout: [xh (bf tier)] | offsets[nrows+1] | sorted_src[ne] | pairs[ne]
    //            | ghist[nbkt] | cbase[nbkt+1] | ccursor[nbkt] | [W1t | W2t (mfma tier)]
    size_t xh_bytes = (((size_t)nrows * D * sizeof(ushort_t)) + 15) & ~(size_t)15;
    size_t csr_bytes = ((size_t)(nrows + 1) + 2 * (size_t)ne + 3 * (size_t)nbkt + 1) * sizeof(int);
    size_t need_fp = csr_bytes;
    size_t need_bf = xh_bytes + csr_bytes;
    size_t wt_bytes = (size_t)D * HSTR * sizeof(ushort_t);   // 34816
    size_t wt_off = (need_bf + 15) & ~(size_t)15;
    size_t need_mfma = wt_off + 2 * wt_bytes;

    const int eblocks = (ne + 256 * EPB - 1) / (256 * EPB);

    bool use_mfma = false;
    ushort_t* w1t = nullptr;
    ushort_t* w2t = nullptr;

    if (nbkt <= MAX_BKT && ws_size >= need_fp) {
        const bool bf = (ws_size >= need_bf);
        use_mfma = (ws_size >= need_mfma);
        char* wp = (char*)d_ws;
        ushort_t* xh = nullptr;
        if (bf) { xh = (ushort_t*)wp; wp += xh_bytes; }
        int* offsets = (int*)wp;
        int* sorted_src = offsets + (nrows + 1);
        int* pairs = sorted_src + ne;
        int* ghist = pairs + ne;
        int* cbase = ghist + nbkt;
        int* ccursor = cbase + (nbkt + 1);
        if (use_mfma) {
            w1t = (ushort_t*)((char*)d_ws + wt_off);
            w2t = (ushort_t*)((char*)d_ws + wt_off + wt_bytes);
        }

        if (bf) {
            int n4 = nrows * (D / 4);
            cast_kernel<<<(n4 + 255) / 256, 256, 0, stream>>>(x, xh, n4);
        }
        if (use_mfma)
            wprep_kernel<<<(D * D + 255) / 256, 256, 0, stream>>>(W1, W2, w1t, w2t);
        zero_kernel<<<(nbkt + 255) / 256, 256, 0, stream>>>(ghist, nbkt);
        coarse_hist_kernel<<<eblocks, 256, 0, stream>>>(ei + ne, ghist, ne, nbkt);
        coarse_scan_kernel<<<1, SCAN_THREADS, 0, stream>>>(ghist, cbase, ccursor,
                                                           offsets, nbkt, nrows, ne);
        coarse_scatter_kernel<<<eblocks, 256, 0, stream>>>(ei, ccursor, pairs, ne, nbkt);
        bucket_csr_kernel<<<nbkt, 256, 0, stream>>>(pairs, cbase, offsets, sorted_src, nrows);

        long long athreads = (long long)nrows * 64;
        int ablocks = (int)((athreads + 255) / 256);
        if (bf)
            agg_kernel<0><<<ablocks, 256, 0, stream>>>(x, xh, sorted_src, offsets, out, nrows);
        else
            agg_kernel<1><<<ablocks, 256, 0, stream>>>(x, nullptr, sorted_src, offsets, out, nrows);
    } else {
        int n4 = nrows * (D / 4);
        init_kernel<<<(n4 + 255) / 256, 256, 0, stream>>>(x, out, n4);
        long long sthreads = (long long)ne * 32;
        scatter_kernel<<<(int)((sthreads + 255) / 256), 256, 0, stream>>>(x, ei, out, ne);
    }

    if (use_mfma) {
        int fblocks = (nrows + MLP_BM - 1) / MLP_BM;
        fused_mlp_kernel<<<fblocks, FMLP_THREADS, 0, stream>>>(out, w1t, w2t, b1, b2, out, nrows);
    } else {
        int mblocks = (nrows + TILE_ROWS - 1) / TILE_ROWS;
        mlp_kernel<true><<<mblocks, MLP_THREADS, 0, stream>>>(out, W1, b1, out, nrows);
        mlp_kernel<false><<<mblocks, MLP_THREADS, 0, stream>>>(out, W2, b2, out, nrows);
    }
}

// Round 8
// 254.041 us; speedup vs baseline: 11.6368x; 1.1581x over previous
//
#include <hip/hip_runtime.h>

#define D 128
#define TILE_ROWS 64
#define MLP_THREADS 512
#define SCAN_THREADS 1024
#define BK_NODES 128     // dst-nodes per coarse bucket
#define MAX_BKT 1024
#define EPB 16           // edges per thread in coarse hist pass
#define SC_THREADS 512
#define SC_EPB 24        // 12288 edges per scatter block
#define CAPL 6144        // LDS staging capacity per bucket in bucket_csr
#define FMLP_THREADS 512
#define MLP_BM 128
#define HSTR 136         // padded LDS row stride (bf16 elems)

typedef unsigned short ushort_t;
typedef unsigned int uint_t;
typedef __attribute__((ext_vector_type(8))) short short8v;   // 8 bf16 (4 VGPR)
typedef __attribute__((ext_vector_type(4))) float f32x4;

__device__ __forceinline__ ushort_t f2bf(float f) {
    uint_t u = __float_as_uint(f);
    u = u + 0x7FFFu + ((u >> 16) & 1u);   // round-to-nearest-even
    return (ushort_t)(u >> 16);
}

// ===========================================================================
// cast: x (fp32) -> xh (bf16), ushort4 stores
// ===========================================================================
__global__ void cast_kernel(const float* __restrict__ x, ushort_t* __restrict__ xh, int n4) {
    int i = blockIdx.x * blockDim.x + threadIdx.x;
    if (i < n4) {
        float4 v = reinterpret_cast<const float4*>(x)[i];
        ushort4 o;
        o.x = f2bf(v.x); o.y = f2bf(v.y); o.z = f2bf(v.z); o.w = f2bf(v.w);
        reinterpret_cast<ushort4*>(xh)[i] = o;
    }
}

// ===========================================================================
// wprep: W (fp32 [k][c]) -> Wt (bf16 [c][HSTR]) for MFMA B-fragments
// ===========================================================================
__global__ void wprep_kernel(const float* __restrict__ W1, const float* __restrict__ W2,
                             ushort_t* __restrict__ w1t, ushort_t* __restrict__ w2t) {
    int i = blockIdx.x * blockDim.x + threadIdx.x;
    if (i < D * D) {
        int c = i & 127, k = i >> 7;
        w1t[(size_t)c * HSTR + k] = f2bf(W1[(size_t)k * D + c]);
        w2t[(size_t)c * HSTR + k] = f2bf(W2[(size_t)k * D + c]);
    }
}

// ===========================================================================
// Coarse CSR build: zero -> hist -> scan -> scatter(LDS-staged) -> bucket(LDS-staged)
// pairs[] holds (src<<7)|(dst&127), grouped by coarse bucket (dst>>7).
// ===========================================================================
__global__ void zero_kernel(int* __restrict__ p, int n) {
    int i = blockIdx.x * blockDim.x + threadIdx.x;
    if (i < n) p[i] = 0;
}

__global__ void coarse_hist_kernel(const int* __restrict__ dsts,
                                   int* __restrict__ ghist, int ne, int nbkt) {
    __shared__ int h[MAX_BKT];
    for (int k = threadIdx.x; k < nbkt; k += blockDim.x) h[k] = 0;
    __syncthreads();
    int base = blockIdx.x * blockDim.x * EPB;
    for (int j = 0; j < EPB; ++j) {
        int e = base + j * blockDim.x + threadIdx.x;
        if (e < ne) atomicAdd(&h[dsts[e] >> 7], 1);
    }
    __syncthreads();
    for (int k = threadIdx.x; k < nbkt; k += blockDim.x)
        if (h[k]) atomicAdd(&ghist[k], h[k]);
}

__global__ __launch_bounds__(SCAN_THREADS) void coarse_scan_kernel(
    const int* __restrict__ ghist, int* __restrict__ cbase,
    int* __restrict__ ccursor, int* __restrict__ offsets,
    int nbkt, int nnodes, int ne) {
    __shared__ int sc[SCAN_THREADS];
    int t = threadIdx.x;
    int v = (t < nbkt) ? ghist[t] : 0;
    sc[t] = v;
    __syncthreads();
    for (int off = 1; off < SCAN_THREADS; off <<= 1) {
        int u = (t >= off) ? sc[t - off] : 0;
        __syncthreads();
        sc[t] += u;
        __syncthreads();
    }
    if (t < nbkt) { cbase[t] = sc[t] - v; ccursor[t] = sc[t] - v; }
    if (t == 0) { cbase[nbkt] = sc[SCAN_THREADS - 1]; offsets[nnodes] = ne; }
}

// LDS-staged scatter: block-local counting sort by bucket into a 48KB LDS
// buffer, then per-bin contiguous copy-out (coalesced segment writes).
__global__ __launch_bounds__(SC_THREADS) void coarse_scatter_kernel(
    const int* __restrict__ ei, int* __restrict__ ccursor,
    int* __restrict__ pairs, int ne, int nbkt) {
    __shared__ int h[MAX_BKT];
    __shared__ int lbase[MAX_BKT];
    __shared__ int gbase[MAX_BKT];
    __shared__ int lcur[MAX_BKT];
    __shared__ int stot[SC_THREADS];
    __shared__ int stage[SC_THREADS * SC_EPB];   // 48 KB

    const int t = threadIdx.x;
    const int base = blockIdx.x * SC_THREADS * SC_EPB;

    for (int k = t; k < MAX_BKT; k += SC_THREADS) h[k] = 0;
    __syncthreads();

    // pass 1: block-local bucket histogram
    for (int j = 0; j < SC_EPB; ++j) {
        int e = base + j * SC_THREADS + t;
        if (e < ne) atomicAdd(&h[ei[ne + e] >> 7], 1);
    }
    __syncthreads();

    // exclusive scan of h[0..1023] (2 bins/thread + Hillis-Steele over totals)
    int a0 = h[2 * t], a1 = h[2 * t + 1];
    stot[t] = a0 + a1;
    __syncthreads();
    for (int off = 1; off < SC_THREADS; off <<= 1) {
        int u = (t >= off) ? stot[t - off] : 0;
        __syncthreads();
        stot[t] += u;
        __syncthreads();
    }
    int bexc = stot[t] - (a0 + a1);
    lbase[2 * t] = bexc;
    lbase[2 * t + 1] = bexc + a0;
    lcur[2 * t] = bexc;
    lcur[2 * t + 1] = bexc + a0;
    __syncthreads();

    // reserve global chunks per bucket
    for (int k = t; k < MAX_BKT; k += SC_THREADS)
        gbase[k] = h[k] ? atomicAdd(&ccursor[k], h[k]) : 0;
    __syncthreads();

    // pass 2: place packed pairs into LDS staging
    for (int j = 0; j < SC_EPB; ++j) {
        int e = base + j * SC_THREADS + t;
        if (e < ne) {
            int dst = ei[ne + e];
            int src = ei[e];
            int k = dst >> 7;
            int pos = atomicAdd(&lcur[k], 1);
            stage[pos] = (src << 7) | (dst & (BK_NODES - 1));
        }
    }
    __syncthreads();

    // copy-out: wave w handles bins w, w+8, ... ; contiguous per-bin segments
    const int lane = t & 63, w = t >> 6;
    for (int k = w; k < nbkt; k += (SC_THREADS / 64)) {
        int cnt = h[k];
        int lb = lbase[k], gb = gbase[k];
        for (int i = lane; i < cnt; i += 64)
            pairs[gb + i] = stage[lb + i];
    }
}

// LDS-staged per-node CSR within each coarse bucket: counting sort into LDS,
// then fully-coalesced stream-out. Scattered fallback if bucket > CAPL.
__global__ void bucket_csr_kernel(const int* __restrict__ pairs,
                                  const int* __restrict__ cbase,
                                  int* __restrict__ offsets,
                                  int* __restrict__ sorted_src,
                                  int nnodes) {
    __shared__ int h[BK_NODES];
    __shared__ int ex[BK_NODES];
    __shared__ int cur[BK_NODES];
    __shared__ int stage[CAPL];      // 24 KB
    int b = blockIdx.x;
    int t = threadIdx.x;
    int rbeg = cbase[b], rend = cbase[b + 1];
    int cnt = rend - rbeg;
    if (t < BK_NODES) h[t] = 0;
    __syncthreads();
    for (int i = rbeg + t; i < rend; i += blockDim.x)
        atomicAdd(&h[pairs[i] & (BK_NODES - 1)], 1);
    __syncthreads();
    if (t < BK_NODES) ex[t] = h[t];
    __syncthreads();
    for (int off = 1; off < BK_NODES; off <<= 1) {
        int u = (t >= off && t < BK_NODES) ? ex[t - off] : 0;
        __syncthreads();
        if (t < BK_NODES) ex[t] += u;
        __syncthreads();
    }
    const bool staged = (cnt <= CAPL);
    if (t < BK_NODES) {
        int e = ex[t] - h[t];          // exclusive within bucket
        cur[t] = staged ? e : rbeg + e;
        int node = b * BK_NODES + t;
        if (node < nnodes) offsets[node] = rbeg + e;
    }
    __syncthreads();
    if (staged) {
        for (int i = rbeg + t; i < rend; i += blockDim.x) {
            int p = pairs[i];
            int pos = atomicAdd(&cur[p & (BK_NODES - 1)], 1);
            stage[pos] = p >> 7;
        }
        __syncthreads();
        for (int i = t; i < cnt; i += blockDim.x)
            sorted_src[rbeg + i] = stage[i];       // coalesced
    } else {
        for (int i = rbeg + t; i < rend; i += blockDim.x) {
            int p = pairs[i];
            int pos = atomicAdd(&cur[p & (BK_NODES - 1)], 1);
            sorted_src[pos] = p >> 7;
        }
    }
}

// ===========================================================================
// agg: one wave per node, unroll x8. MODE 0: bf16 gather + bf16 self-term;
// MODE 1: fp32. fp32 accumulate, fp32 output.
// ===========================================================================
template <int MODE>
__global__ void agg_kernel(const float* __restrict__ x,
                           const ushort_t* __restrict__ xh,
                           const int* __restrict__ sorted_src,
                           const int* __restrict__ offsets,
                           float* __restrict__ out, int nnodes) {
    int gid = blockIdx.x * blockDim.x + threadIdx.x;
    int node = gid >> 6;
    if (node >= nnodes) return;
    int lane = threadIdx.x & 63;
    int beg = offsets[node];
    int end = offsets[node + 1];
    float sx, sy;
    int i = beg;
    if (MODE == 0) {
        const uint_t* xp = reinterpret_cast<const uint_t*>(xh);  // 64 uints/row
        uint_t us = xp[(size_t)node * 64 + lane];
        sx = __uint_as_float(us << 16);
        sy = __uint_as_float(us & 0xffff0000u);
        for (; i + 8 <= end; i += 8) {
            int s0 = sorted_src[i + 0], s1 = sorted_src[i + 1];
            int s2 = sorted_src[i + 2], s3 = sorted_src[i + 3];
            int s4 = sorted_src[i + 4], s5 = sorted_src[i + 5];
            int s6 = sorted_src[i + 6], s7 = sorted_src[i + 7];
            uint_t u0 = xp[(size_t)s0 * 64 + lane];
            uint_t u1 = xp[(size_t)s1 * 64 + lane];
            uint_t u2 = xp[(size_t)s2 * 64 + lane];
            uint_t u3 = xp[(size_t)s3 * 64 + lane];
            uint_t u4 = xp[(size_t)s4 * 64 + lane];
            uint_t u5 = xp[(size_t)s5 * 64 + lane];
            uint_t u6 = xp[(size_t)s6 * 64 + lane];
            uint_t u7 = xp[(size_t)s7 * 64 + lane];
            sx += __uint_as_float(u0 << 16) + __uint_as_float(u1 << 16) +
                  __uint_as_float(u2 << 16) + __uint_as_float(u3 << 16) +
                  __uint_as_float(u4 << 16) + __uint_as_float(u5 << 16) +
                  __uint_as_float(u6 << 16) + __uint_as_float(u7 << 16);
            sy += __uint_as_float(u0 & 0xffff0000u) + __uint_as_float(u1 & 0xffff0000u) +
                  __uint_as_float(u2 & 0xffff0000u) + __uint_as_float(u3 & 0xffff0000u) +
                  __uint_as_float(u4 & 0xffff0000u) + __uint_as_float(u5 & 0xffff0000u) +
                  __uint_as_float(u6 & 0xffff0000u) + __uint_as_float(u7 & 0xffff0000u);
        }
        for (; i < end; ++i) {
            uint_t u = xp[(size_t)sorted_src[i] * 64 + lane];
            sx += __uint_as_float(u << 16);
            sy += __uint_as_float(u & 0xffff0000u);
        }
    } else {
        const float2* xp = reinterpret_cast<const float2*>(x);
        float2 a = xp[(size_t)node * 64 + lane];
        sx = a.x; sy = a.y;
        for (; i + 8 <= end; i += 8) {
            int s0 = sorted_src[i + 0], s1 = sorted_src[i + 1];
            int s2 = sorted_src[i + 2], s3 = sorted_src[i + 3];
            int s4 = sorted_src[i + 4], s5 = sorted_src[i + 5];
            int s6 = sorted_src[i + 6], s7 = sorted_src[i + 7];
            float2 v0 = xp[(size_t)s0 * 64 + lane];
            float2 v1 = xp[(size_t)s1 * 64 + lane];
            float2 v2 = xp[(size_t)s2 * 64 + lane];
            float2 v3 = xp[(size_t)s3 * 64 + lane];
            float2 v4 = xp[(size_t)s4 * 64 + lane];
            float2 v5 = xp[(size_t)s5 * 64 + lane];
            float2 v6 = xp[(size_t)s6 * 64 + lane];
            float2 v7 = xp[(size_t)s7 * 64 + lane];
            sx += ((v0.x + v1.x) + (v2.x + v3.x)) + ((v4.x + v5.x) + (v6.x + v7.x));
            sy += ((v0.y + v1.y) + (v2.y + v3.y)) + ((v4.y + v5.y) + (v6.y + v7.y));
        }
        for (; i < end; ++i) {
            float2 v = xp[(size_t)sorted_src[i] * 64 + lane];
            sx += v.x;
            sy += v.y;
        }
    }
    float2 o;
    o.x = sx;
    o.y = sy;
    reinterpret_cast<float2*>(out)[(size_t)node * 64 + lane] = o;
}

// ===========================================================================
// fused_mlp: out = relu(h@W1+b1)@W2+b2, bf16 MFMA, in-place on d_out.
// ===========================================================================
__global__ __launch_bounds__(FMLP_THREADS, 1) void fused_mlp_kernel(
    const float* __restrict__ h, const ushort_t* __restrict__ w1t,
    const ushort_t* __restrict__ w2t, const float* __restrict__ b1,
    const float* __restrict__ b2, float* __restrict__ outp, int nrows) {
    __shared__ ushort_t sh[MLP_BM * HSTR];
    __shared__ ushort_t sw1[D * HSTR];
    __shared__ ushort_t sw2[D * HSTR];
    const int tid = threadIdx.x;
    const int row0 = blockIdx.x * MLP_BM;

    {
        const uint4* s1 = reinterpret_cast<const uint4*>(w1t);
        const uint4* s2 = reinterpret_cast<const uint4*>(w2t);
        uint4* d1 = reinterpret_cast<uint4*>(sw1);
        uint4* d2 = reinterpret_cast<uint4*>(sw2);
        for (int i = tid; i < D * HSTR / 8; i += FMLP_THREADS) { d1[i] = s1[i]; d2[i] = s2[i]; }
    }
    for (int i = tid; i < MLP_BM * 32; i += FMLP_THREADS) {
        int r = i >> 5, c4 = i & 31;
        float4 v = make_float4(0.f, 0.f, 0.f, 0.f);
        if (row0 + r < nrows)
            v = reinterpret_cast<const float4*>(h + (size_t)(row0 + r) * D)[c4];
        ushort4 o;
        o.x = f2bf(v.x); o.y = f2bf(v.y); o.z = f2bf(v.z); o.w = f2bf(v.w);
        *reinterpret_cast<ushort4*>(&sh[r * HSTR + c4 * 4]) = o;
    }
    __syncthreads();

    const int w = tid >> 6, l = tid & 63;
    const int lr = l & 15, lg = l >> 4;
    const int rowb = w * 16;

    // ---- layer 1 ----
    short8v A[4];
#pragma unroll
    for (int kk = 0; kk < 4; ++kk)
        A[kk] = *reinterpret_cast<const short8v*>(&sh[(rowb + lr) * HSTR + kk * 32 + lg * 8]);
#pragma unroll
    for (int n = 0; n < 8; ++n) {
        float bv = b1[n * 16 + lr];
        f32x4 acc = {bv, bv, bv, bv};
#pragma unroll
        for (int kk = 0; kk < 4; ++kk) {
            short8v B = *reinterpret_cast<const short8v*>(&sw1[(n * 16 + lr) * HSTR + kk * 32 + lg * 8]);
            acc = __builtin_amdgcn_mfma_f32_16x16x32_bf16(A[kk], B, acc, 0, 0, 0);
        }
#pragma unroll
        for (int r = 0; r < 4; ++r) {
            float v = fmaxf(acc[r], 0.f);
            sh[(rowb + lg * 4 + r) * HSTR + n * 16 + lr] = f2bf(v);
        }
    }

    // ---- layer 2 (wave-local rows; no block barrier needed) ----
    short8v A2[4];
#pragma unroll
    for (int kk = 0; kk < 4; ++kk)
        A2[kk] = *reinterpret_cast<const short8v*>(&sh[(rowb + lr) * HSTR + kk * 32 + lg * 8]);
#pragma unroll
    for (int n = 0; n < 8; ++n) {
        float bv = b2[n * 16 + lr];
        f32x4 acc = {bv, bv, bv, bv};
#pragma unroll
        for (int kk = 0; kk < 4; ++kk) {
            short8v B = *reinterpret_cast<const short8v*>(&sw2[(n * 16 + lr) * HSTR + kk * 32 + lg * 8]);
            acc = __builtin_amdgcn_mfma_f32_16x16x32_bf16(A2[kk], B, acc, 0, 0, 0);
        }
#pragma unroll
        for (int r = 0; r < 4; ++r) {
            int grow = row0 + rowb + lg * 4 + r;
            if (grow < nrows)
                outp[(size_t)grow * D + n * 16 + lr] = acc[r];
        }
    }
}

// ===========================================================================
// Fallback: init + fp32 atomic scatter
// ===========================================================================
__global__ void init_kernel(const float* __restrict__ x, float* __restrict__ out, int n4) {
    int i = blockIdx.x * blockDim.x + threadIdx.x;
    if (i < n4) {
        reinterpret_cast<float4*>(out)[i] = reinterpret_cast<const float4*>(x)[i];
    }
}

__global__ void scatter_kernel(const float* __restrict__ x,
                               const int* __restrict__ ei,
                               float* __restrict__ out, int ne) {
    long long gid = (long long)blockIdx.x * blockDim.x + threadIdx.x;
    int e = (int)(gid >> 5);
    if (e >= ne) return;
    int d0 = ((int)gid & 31) * 4;
    int src = ei[e];
    int dst = ei[ne + e];
    float4 v = *reinterpret_cast<const float4*>(x + (long long)src * D + d0);
    float* o = out + (long long)dst * D + d0;
    atomicAdd(o + 0, v.x);
    atomicAdd(o + 1, v.y);
    atomicAdd(o + 2, v.z);
    atomicAdd(o + 3, v.w);
}

// ===========================================================================
// Fallback MLP: fp32 in-place row-tile GEMM
// ===========================================================================
template <bool RELU>
__global__ __launch_bounds__(MLP_THREADS, 1) void mlp_kernel(
    const float* __restrict__ in, const float* __restrict__ W,
    const float* __restrict__ b, float* __restrict__ outp, int nrows) {
    __shared__ float Wl[D][D];
    __shared__ float inl[TILE_ROWS][D + 4];

    const int tid = threadIdx.x;
    const int row0 = blockIdx.x * TILE_ROWS;

    for (int i = tid; i < D * D / 4; i += MLP_THREADS) {
        reinterpret_cast<float4*>(&Wl[0][0])[i] =
            reinterpret_cast<const float4*>(W)[i];
    }
    for (int i = tid; i < TILE_ROWS * (D / 4); i += MLP_THREADS) {
        int r = i >> 5;
        int k4 = i & 31;
        float4 v = make_float4(0.f, 0.f, 0.f, 0.f);
        if (row0 + r < nrows)
            v = *reinterpret_cast<const float4*>(in + (size_t)(row0 + r) * D + 4 * k4);
        *reinterpret_cast<float4*>(&inl[r][4 * k4]) = v;
    }
    __syncthreads();

    const int cg = tid & 31;
    const int rg = tid >> 5;
    const int c0 = cg * 4;
    const int r0 = rg * 4;

    float4 bv = *reinterpret_cast<const float4*>(b + c0);
    float acc[4][4];
#pragma unroll
    for (int i = 0; i < 4; ++i) {
        acc[i][0] = bv.x; acc[i][1] = bv.y; acc[i][2] = bv.z; acc[i][3] = bv.w;
    }

#pragma unroll 4
    for (int k4 = 0; k4 < 32; ++k4) {
        float4 w0 = *reinterpret_cast<const float4*>(&Wl[4 * k4 + 0][c0]);
        float4 w1 = *reinterpret_cast<const float4*>(&Wl[4 * k4 + 1][c0]);
        float4 w2 = *reinterpret_cast<const float4*>(&Wl[4 * k4 + 2][c0]);
        float4 w3 = *reinterpret_cast<const float4*>(&Wl[4 * k4 + 3][c0]);
#pragma unroll
        for (int i = 0; i < 4; ++i) {
            float4 a = *reinterpret_cast<const float4*>(&inl[r0 + i][4 * k4]);
            acc[i][0] += a.x * w0.x + a.y * w1.x + a.z * w2.x + a.w * w3.x;
            acc[i][1] += a.x * w0.y + a.y * w1.y + a.z * w2.y + a.w * w3.y;
            acc[i][2] += a.x * w0.z + a.y * w1.z + a.z * w2.z + a.w * w3.z;
            acc[i][3] += a.x * w0.w + a.y * w1.w + a.z * w2.w + a.w * w3.w;
        }
    }

#pragma unroll
    for (int i = 0; i < 4; ++i) {
        int r = row0 + r0 + i;
        if (r < nrows) {
            float4 o;
            if (RELU) {
                o.x = fmaxf(acc[i][0], 0.f); o.y = fmaxf(acc[i][1], 0.f);
                o.z = fmaxf(acc[i][2], 0.f); o.w = fmaxf(acc[i][3], 0.f);
            } else {
                o.x = acc[i][0]; o.y = acc[i][1]; o.z = acc[i][2]; o.w = acc[i][3];
            }
            *reinterpret_cast<float4*>(outp + (size_t)r * D + c0) = o;
        }
    }
}

extern "C" void kernel_launch(void* const* d_in, const int* in_sizes, int n_in,
                              void* d_out, int out_size, void* d_ws, size_t ws_size,
                              hipStream_t stream) {
    const float* x = (const float*)d_in[0];
    const int* ei = (const int*)d_in[1];
    const float* W1 = (const float*)d_in[2];
    const float* b1 = (const float*)d_in[3];
    const float* W2 = (const float*)d_in[4];
    const float* b2 = (const float*)d_in[5];
    float* out = (float*)d_out;

    const int nrows = in_sizes[0] / D;     // 100000 nodes
    const int ne = in_sizes[1] / 2;        // 3200000 edges
    const int nbkt = (nrows + BK_NODES - 1) / BK_NODES;

    // ws layout: [xh (bf tier)] | offsets[nrows+1] | sorted_src[ne] | pairs[ne]
    //            | ghist[nbkt] | cbase[nbkt+1] | ccursor[nbkt] | [W1t | W2t (mfma tier)]
    size_t xh_bytes = (((size_t)nrows * D * sizeof(ushort_t)) + 15) & ~(size_t)15;
    size_t csr_bytes = ((size_t)(nrows + 1) + 2 * (size_t)ne + 3 * (size_t)nbkt + 1) * sizeof(int);
    size_t need_fp = csr_bytes;
    size_t need_bf = xh_bytes + csr_bytes;
    size_t wt_bytes = (size_t)D * HSTR * sizeof(ushort_t);   // 34816
    size_t wt_off = (need_bf + 15) & ~(size_t)15;
    size_t need_mfma = wt_off + 2 * wt_bytes;

    const int hblocks = (ne + 256 * EPB - 1) / (256 * EPB);
    const int sblocks2 = (ne + SC_THREADS * SC_EPB - 1) / (SC_THREADS * SC_EPB);

    bool use_mfma = false;
    ushort_t* w1t = nullptr;
    ushort_t* w2t = nullptr;

    if (nbkt <= MAX_BKT && ws_size >= need_fp) {
        const bool bf = (ws_size >= need_bf);
        use_mfma = (ws_size >= need_mfma);
        char* wp = (char*)d_ws;
        ushort_t* xh = nullptr;
        if (bf) { xh = (ushort_t*)wp; wp += xh_bytes; }
        int* offsets = (int*)wp;
        int* sorted_src = offsets + (nrows + 1);
        int* pairs = sorted_src + ne;
        int* ghist = pairs + ne;
        int* cbase = ghist + nbkt;
        int* ccursor = cbase + (nbkt + 1);
        if (use_mfma) {
            w1t = (ushort_t*)((char*)d_ws + wt_off);
            w2t = (ushort_t*)((char*)d_ws + wt_off + wt_bytes);
        }

        if (bf) {
            int n4 = nrows * (D / 4);
            cast_kernel<<<(n4 + 255) / 256, 256, 0, stream>>>(x, xh, n4);
        }
        if (use_mfma)
            wprep_kernel<<<(D * D + 255) / 256, 256, 0, stream>>>(W1, W2, w1t, w2t);
        zero_kernel<<<(nbkt + 255) / 256, 256, 0, stream>>>(ghist, nbkt);
        coarse_hist_kernel<<<hblocks, 256, 0, stream>>>(ei + ne, ghist, ne, nbkt);
        coarse_scan_kernel<<<1, SCAN_THREADS, 0, stream>>>(ghist, cbase, ccursor,
                                                           offsets, nbkt, nrows, ne);
        coarse_scatter_kernel<<<sblocks2, SC_THREADS, 0, stream>>>(ei, ccursor, pairs, ne, nbkt);
        bucket_csr_kernel<<<nbkt, 256, 0, stream>>>(pairs, cbase, offsets, sorted_src, nrows);

        long long athreads = (long long)nrows * 64;
        int ablocks = (int)((athreads + 255) / 256);
        if (bf)
            agg_kernel<0><<<ablocks, 256, 0, stream>>>(x, xh, sorted_src, offsets, out, nrows);
        else
            agg_kernel<1><<<ablocks, 256, 0, stream>>>(x, nullptr, sorted_src, offsets, out, nrows);
    } else {
        int n4 = nrows * (D / 4);
        init_kernel<<<(n4 + 255) / 256, 256, 0, stream>>>(x, out, n4);
        long long sthreads = (long long)ne * 32;
        scatter_kernel<<<(int)((sthreads + 255) / 256), 256, 0, stream>>>(x, ei, out, ne);
    }

    if (use_mfma) {
        int fblocks = (nrows + MLP_BM - 1) / MLP_BM;
        fused_mlp_kernel<<<fblocks, FMLP_THREADS, 0, stream>>>(out, w1t, w2t, b1, b2, out, nrows);
    } else {
        int mblocks = (nrows + TILE_ROWS - 1) / TILE_ROWS;
        mlp_kernel<true><<<mblocks, MLP_THREADS, 0, stream>>>(out, W1, b1, out, nrows);
        mlp_kernel<false><<<mblocks, MLP_THREADS, 0, stream>>>(out, W2, b2, out, nrows);
    }
}

// Round 9
// 244.637 us; speedup vs baseline: 12.0842x; 1.0384x over previous
//
#include <hip/hip_runtime.h>

#define D 128
#define TILE_ROWS 64
#define MLP_THREADS 512
#define SCAN_THREADS 1024
#define BK_NODES 128     // dst-nodes per coarse bucket
#define MAX_BKT 1024
#define EPB 16           // edges per thread in coarse hist pass
#define SC_THREADS 512
#define SC_EPB 24        // 12288 edges per scatter block
#define CAPL 6144        // LDS staging capacity per bucket in bucket_csr
#define FMLP_THREADS 512
#define MLP_BM 128
#define HSTR 136         // padded LDS row stride (bf16 elems)

typedef unsigned short ushort_t;
typedef unsigned int uint_t;
typedef __attribute__((ext_vector_type(8))) short short8v;   // 8 bf16 (4 VGPR)
typedef __attribute__((ext_vector_type(4))) float f32x4;

__device__ __forceinline__ ushort_t f2bf(float f) {
    uint_t u = __float_as_uint(f);
    u = u + 0x7FFFu + ((u >> 16) & 1u);   // round-to-nearest-even
    return (ushort_t)(u >> 16);
}
__device__ __forceinline__ float bf_lo(uint_t u) { return __uint_as_float(u << 16); }
__device__ __forceinline__ float bf_hi(uint_t u) { return __uint_as_float(u & 0xffff0000u); }

// ===========================================================================
// cast: x (fp32) -> xh (bf16), ushort4 stores
// ===========================================================================
__global__ void cast_kernel(const float* __restrict__ x, ushort_t* __restrict__ xh, int n4) {
    int i = blockIdx.x * blockDim.x + threadIdx.x;
    if (i < n4) {
        float4 v = reinterpret_cast<const float4*>(x)[i];
        ushort4 o;
        o.x = f2bf(v.x); o.y = f2bf(v.y); o.z = f2bf(v.z); o.w = f2bf(v.w);
        reinterpret_cast<ushort4*>(xh)[i] = o;
    }
}

// ===========================================================================
// wprep: W (fp32 [k][c]) -> Wt (bf16 [c][HSTR]) for MFMA B-fragments
// ===========================================================================
__global__ void wprep_kernel(const float* __restrict__ W1, const float* __restrict__ W2,
                             ushort_t* __restrict__ w1t, ushort_t* __restrict__ w2t) {
    int i = blockIdx.x * blockDim.x + threadIdx.x;
    if (i < D * D) {
        int c = i & 127, k = i >> 7;
        w1t[(size_t)c * HSTR + k] = f2bf(W1[(size_t)k * D + c]);
        w2t[(size_t)c * HSTR + k] = f2bf(W2[(size_t)k * D + c]);
    }
}

// ===========================================================================
// Coarse CSR build: zero -> hist -> scan -> scatter(LDS-staged) -> bucket(LDS-staged)
// ===========================================================================
__global__ void zero_kernel(int* __restrict__ p, int n) {
    int i = blockIdx.x * blockDim.x + threadIdx.x;
    if (i < n) p[i] = 0;
}

__global__ void coarse_hist_kernel(const int* __restrict__ dsts,
                                   int* __restrict__ ghist, int ne, int nbkt) {
    __shared__ int h[MAX_BKT];
    for (int k = threadIdx.x; k < nbkt; k += blockDim.x) h[k] = 0;
    __syncthreads();
    int base = blockIdx.x * blockDim.x * EPB;
    for (int j = 0; j < EPB; ++j) {
        int e = base + j * blockDim.x + threadIdx.x;
        if (e < ne) atomicAdd(&h[dsts[e] >> 7], 1);
    }
    __syncthreads();
    for (int k = threadIdx.x; k < nbkt; k += blockDim.x)
        if (h[k]) atomicAdd(&ghist[k], h[k]);
}

__global__ __launch_bounds__(SCAN_THREADS) void coarse_scan_kernel(
    const int* __restrict__ ghist, int* __restrict__ cbase,
    int* __restrict__ ccursor, int* __restrict__ offsets,
    int nbkt, int nnodes, int ne) {
    __shared__ int sc[SCAN_THREADS];
    int t = threadIdx.x;
    int v = (t < nbkt) ? ghist[t] : 0;
    sc[t] = v;
    __syncthreads();
    for (int off = 1; off < SCAN_THREADS; off <<= 1) {
        int u = (t >= off) ? sc[t - off] : 0;
        __syncthreads();
        sc[t] += u;
        __syncthreads();
    }
    if (t < nbkt) { cbase[t] = sc[t] - v; ccursor[t] = sc[t] - v; }
    if (t == 0) { cbase[nbkt] = sc[SCAN_THREADS - 1]; offsets[nnodes] = ne; }
}

__global__ __launch_bounds__(SC_THREADS) void coarse_scatter_kernel(
    const int* __restrict__ ei, int* __restrict__ ccursor,
    int* __restrict__ pairs, int ne, int nbkt) {
    __shared__ int h[MAX_BKT];
    __shared__ int lbase[MAX_BKT];
    __shared__ int gbase[MAX_BKT];
    __shared__ int lcur[MAX_BKT];
    __shared__ int stot[SC_THREADS];
    __shared__ int stage[SC_THREADS * SC_EPB];   // 48 KB

    const int t = threadIdx.x;
    const int base = blockIdx.x * SC_THREADS * SC_EPB;

    for (int k = t; k < MAX_BKT; k += SC_THREADS) h[k] = 0;
    __syncthreads();

    for (int j = 0; j < SC_EPB; ++j) {
        int e = base + j * SC_THREADS + t;
        if (e < ne) atomicAdd(&h[ei[ne + e] >> 7], 1);
    }
    __syncthreads();

    int a0 = h[2 * t], a1 = h[2 * t + 1];
    stot[t] = a0 + a1;
    __syncthreads();
    for (int off = 1; off < SC_THREADS; off <<= 1) {
        int u = (t >= off) ? stot[t - off] : 0;
        __syncthreads();
        stot[t] += u;
        __syncthreads();
    }
    int bexc = stot[t] - (a0 + a1);
    lbase[2 * t] = bexc;
    lbase[2 * t + 1] = bexc + a0;
    lcur[2 * t] = bexc;
    lcur[2 * t + 1] = bexc + a0;
    __syncthreads();

    for (int k = t; k < MAX_BKT; k += SC_THREADS)
        gbase[k] = h[k] ? atomicAdd(&ccursor[k], h[k]) : 0;
    __syncthreads();

    for (int j = 0; j < SC_EPB; ++j) {
        int e = base + j * SC_THREADS + t;
        if (e < ne) {
            int dst = ei[ne + e];
            int src = ei[e];
            int k = dst >> 7;
            int pos = atomicAdd(&lcur[k], 1);
            stage[pos] = (src << 7) | (dst & (BK_NODES - 1));
        }
    }
    __syncthreads();

    const int lane = t & 63, w = t >> 6;
    for (int k = w; k < nbkt; k += (SC_THREADS / 64)) {
        int cnt = h[k];
        int lb = lbase[k], gb = gbase[k];
        for (int i = lane; i < cnt; i += 64)
            pairs[gb + i] = stage[lb + i];
    }
}

__global__ void bucket_csr_kernel(const int* __restrict__ pairs,
                                  const int* __restrict__ cbase,
                                  int* __restrict__ offsets,
                                  int* __restrict__ sorted_src,
                                  int nnodes) {
    __shared__ int h[BK_NODES];
    __shared__ int ex[BK_NODES];
    __shared__ int cur[BK_NODES];
    __shared__ int stage[CAPL];      // 24 KB
    int b = blockIdx.x;
    int t = threadIdx.x;
    int rbeg = cbase[b], rend = cbase[b + 1];
    int cnt = rend - rbeg;
    if (t < BK_NODES) h[t] = 0;
    __syncthreads();
    for (int i = rbeg + t; i < rend; i += blockDim.x)
        atomicAdd(&h[pairs[i] & (BK_NODES - 1)], 1);
    __syncthreads();
    if (t < BK_NODES) ex[t] = h[t];
    __syncthreads();
    for (int off = 1; off < BK_NODES; off <<= 1) {
        int u = (t >= off && t < BK_NODES) ? ex[t - off] : 0;
        __syncthreads();
        if (t < BK_NODES) ex[t] += u;
        __syncthreads();
    }
    const bool staged = (cnt <= CAPL);
    if (t < BK_NODES) {
        int e = ex[t] - h[t];
        cur[t] = staged ? e : rbeg + e;
        int node = b * BK_NODES + t;
        if (node < nnodes) offsets[node] = rbeg + e;
    }
    __syncthreads();
    if (staged) {
        for (int i = rbeg + t; i < rend; i += blockDim.x) {
            int p = pairs[i];
            int pos = atomicAdd(&cur[p & (BK_NODES - 1)], 1);
            stage[pos] = p >> 7;
        }
        __syncthreads();
        for (int i = t; i < cnt; i += blockDim.x)
            sorted_src[rbeg + i] = stage[i];
    } else {
        for (int i = rbeg + t; i < rend; i += blockDim.x) {
            int p = pairs[i];
            int pos = atomicAdd(&cur[p & (BK_NODES - 1)], 1);
            sorted_src[pos] = p >> 7;
        }
    }
}

// ===========================================================================
// agg MODE 0 (bf16): one wave per node; TWO src rows per load instruction.
// Lane l: half = l>>5 (src parity), col = l&31 (uint-pair -> dims 4*col..+3).
// uint2 load = 8B/lane -> 512B (2 rows) per instruction; 8 loads in flight.
// Halves combined via 4x shfl_xor(32). Output: bf16 h to hbf (if given) or
// fp32 to out.
// ===========================================================================
__global__ void agg_bf_kernel(const ushort_t* __restrict__ xh,
                              const int* __restrict__ sorted_src,
                              const int* __restrict__ offsets,
                              float* __restrict__ out,
                              uint_t* __restrict__ hbf, int nnodes) {
    int gid = blockIdx.x * blockDim.x + threadIdx.x;
    int node = gid >> 6;
    if (node >= nnodes) return;
    const int lane = threadIdx.x & 63;
    const int col = lane & 31;
    const int half = lane >> 5;
    const uint2* xp = reinterpret_cast<const uint2*>(xh);   // 32 uint2 per row
    int beg = offsets[node];
    int end = offsets[node + 1];

    float s0, s1, s2, s3;
    {
        uint2 u = xp[(size_t)node * 32 + col];
        if (half) { u.x = 0u; u.y = 0u; }     // self term counted once
        s0 = bf_lo(u.x); s1 = bf_hi(u.x);
        s2 = bf_lo(u.y); s3 = bf_hi(u.y);
    }

    int i = beg;
    for (; i + 16 <= end; i += 16) {
        uint2 v0 = xp[(size_t)sorted_src[i + 0 + half] * 32 + col];
        uint2 v1 = xp[(size_t)sorted_src[i + 2 + half] * 32 + col];
        uint2 v2 = xp[(size_t)sorted_src[i + 4 + half] * 32 + col];
        uint2 v3 = xp[(size_t)sorted_src[i + 6 + half] * 32 + col];
        uint2 v4 = xp[(size_t)sorted_src[i + 8 + half] * 32 + col];
        uint2 v5 = xp[(size_t)sorted_src[i + 10 + half] * 32 + col];
        uint2 v6 = xp[(size_t)sorted_src[i + 12 + half] * 32 + col];
        uint2 v7 = xp[(size_t)sorted_src[i + 14 + half] * 32 + col];
        s0 += bf_lo(v0.x) + bf_lo(v1.x) + bf_lo(v2.x) + bf_lo(v3.x) +
              bf_lo(v4.x) + bf_lo(v5.x) + bf_lo(v6.x) + bf_lo(v7.x);
        s1 += bf_hi(v0.x) + bf_hi(v1.x) + bf_hi(v2.x) + bf_hi(v3.x) +
              bf_hi(v4.x) + bf_hi(v5.x) + bf_hi(v6.x) + bf_hi(v7.x);
        s2 += bf_lo(v0.y) + bf_lo(v1.y) + bf_lo(v2.y) + bf_lo(v3.y) +
              bf_lo(v4.y) + bf_lo(v5.y) + bf_lo(v6.y) + bf_lo(v7.y);
        s3 += bf_hi(v0.y) + bf_hi(v1.y) + bf_hi(v2.y) + bf_hi(v3.y) +
              bf_hi(v4.y) + bf_hi(v5.y) + bf_hi(v6.y) + bf_hi(v7.y);
    }
    for (; i + 2 <= end; i += 2) {
        uint2 u = xp[(size_t)sorted_src[i + half] * 32 + col];
        s0 += bf_lo(u.x); s1 += bf_hi(u.x);
        s2 += bf_lo(u.y); s3 += bf_hi(u.y);
    }
    if (i < end && half == 0) {
        uint2 u = xp[(size_t)sorted_src[i] * 32 + col];
        s0 += bf_lo(u.x); s1 += bf_hi(u.x);
        s2 += bf_lo(u.y); s3 += bf_hi(u.y);
    }

    s0 += __shfl_xor(s0, 32);
    s1 += __shfl_xor(s1, 32);
    s2 += __shfl_xor(s2, 32);
    s3 += __shfl_xor(s3, 32);

    if (half == 0) {
        if (hbf) {
            uint_t lo = (uint_t)f2bf(s0) | ((uint_t)f2bf(s1) << 16);
            uint_t hi = (uint_t)f2bf(s2) | ((uint_t)f2bf(s3) << 16);
            uint2 o; o.x = lo; o.y = hi;
            reinterpret_cast<uint2*>(hbf)[(size_t)node * 32 + col] = o;
        } else {
            float4 o; o.x = s0; o.y = s1; o.z = s2; o.w = s3;
            reinterpret_cast<float4*>(out + (size_t)node * D)[col] = o;
        }
    }
}

// fp32 fallback agg (round-6 proven): one wave/node, float2/lane, unroll x8
__global__ void agg_fp_kernel(const float* __restrict__ x,
                              const int* __restrict__ sorted_src,
                              const int* __restrict__ offsets,
                              float* __restrict__ out, int nnodes) {
    int gid = blockIdx.x * blockDim.x + threadIdx.x;
    int node = gid >> 6;
    if (node >= nnodes) return;
    int lane = threadIdx.x & 63;
    int beg = offsets[node];
    int end = offsets[node + 1];
    const float2* xp = reinterpret_cast<const float2*>(x);
    float2 a = xp[(size_t)node * 64 + lane];
    float sx = a.x, sy = a.y;
    int i = beg;
    for (; i + 8 <= end; i += 8) {
        int s0 = sorted_src[i + 0], s1 = sorted_src[i + 1];
        int s2 = sorted_src[i + 2], s3 = sorted_src[i + 3];
        int s4 = sorted_src[i + 4], s5 = sorted_src[i + 5];
        int s6 = sorted_src[i + 6], s7 = sorted_src[i + 7];
        float2 v0 = xp[(size_t)s0 * 64 + lane];
        float2 v1 = xp[(size_t)s1 * 64 + lane];
        float2 v2 = xp[(size_t)s2 * 64 + lane];
        float2 v3 = xp[(size_t)s3 * 64 + lane];
        float2 v4 = xp[(size_t)s4 * 64 + lane];
        float2 v5 = xp[(size_t)s5 * 64 + lane];
        float2 v6 = xp[(size_t)s6 * 64 + lane];
        float2 v7 = xp[(size_t)s7 * 64 + lane];
        sx += ((v0.x + v1.x) + (v2.x + v3.x)) + ((v4.x + v5.x) + (v6.x + v7.x));
        sy += ((v0.y + v1.y) + (v2.y + v3.y)) + ((v4.y + v5.y) + (v6.y + v7.y));
    }
    for (; i < end; ++i) {
        float2 v = xp[(size_t)sorted_src[i] * 64 + lane];
        sx += v.x;
        sy += v.y;
    }
    float2 o; o.x = sx; o.y = sy;
    reinterpret_cast<float2*>(out)[(size_t)node * 64 + lane] = o;
}

// ===========================================================================
// fused_mlp: out = relu(h@W1+b1)@W2+b2, bf16 MFMA.
// BF=true: h staged from hbf (bf16, direct copy). BF=false: from fp32 h.
// ===========================================================================
template <bool BF>
__global__ __launch_bounds__(FMLP_THREADS, 1) void fused_mlp_kernel(
    const float* __restrict__ h, const uint_t* __restrict__ hbf,
    const ushort_t* __restrict__ w1t, const ushort_t* __restrict__ w2t,
    const float* __restrict__ b1, const float* __restrict__ b2,
    float* __restrict__ outp, int nrows) {
    __shared__ ushort_t sh[MLP_BM * HSTR];
    __shared__ ushort_t sw1[D * HSTR];
    __shared__ ushort_t sw2[D * HSTR];
    const int tid = threadIdx.x;
    const int row0 = blockIdx.x * MLP_BM;

    {
        const uint4* s1 = reinterpret_cast<const uint4*>(w1t);
        const uint4* s2 = reinterpret_cast<const uint4*>(w2t);
        uint4* d1 = reinterpret_cast<uint4*>(sw1);
        uint4* d2 = reinterpret_cast<uint4*>(sw2);
        for (int i = tid; i < D * HSTR / 8; i += FMLP_THREADS) { d1[i] = s1[i]; d2[i] = s2[i]; }
    }
    if (BF) {
        // 16 uint4 per row (64 uints = 128 bf16)
        for (int i = tid; i < MLP_BM * 16; i += FMLP_THREADS) {
            int r = i >> 4, c = i & 15;
            uint4 v = make_uint4(0u, 0u, 0u, 0u);
            if (row0 + r < nrows)
                v = reinterpret_cast<const uint4*>(hbf + (size_t)(row0 + r) * 64)[c];
            *reinterpret_cast<uint4*>(&sh[r * HSTR + c * 8]) = v;
        }
    } else {
        for (int i = tid; i < MLP_BM * 32; i += FMLP_THREADS) {
            int r = i >> 5, c4 = i & 31;
            float4 v = make_float4(0.f, 0.f, 0.f, 0.f);
            if (row0 + r < nrows)
                v = reinterpret_cast<const float4*>(h + (size_t)(row0 + r) * D)[c4];
            ushort4 o;
            o.x = f2bf(v.x); o.y = f2bf(v.y); o.z = f2bf(v.z); o.w = f2bf(v.w);
            *reinterpret_cast<ushort4*>(&sh[r * HSTR + c4 * 4]) = o;
        }
    }
    __syncthreads();

    const int w = tid >> 6, l = tid & 63;
    const int lr = l & 15, lg = l >> 4;
    const int rowb = w * 16;

    // ---- layer 1 ----
    short8v A[4];
#pragma unroll
    for (int kk = 0; kk < 4; ++kk)
        A[kk] = *reinterpret_cast<const short8v*>(&sh[(rowb + lr) * HSTR + kk * 32 + lg * 8]);
#pragma unroll
    for (int n = 0; n < 8; ++n) {
        float bv = b1[n * 16 + lr];
        f32x4 acc = {bv, bv, bv, bv};
#pragma unroll
        for (int kk = 0; kk < 4; ++kk) {
            short8v B = *reinterpret_cast<const short8v*>(&sw1[(n * 16 + lr) * HSTR + kk * 32 + lg * 8]);
            acc = __builtin_amdgcn_mfma_f32_16x16x32_bf16(A[kk], B, acc, 0, 0, 0);
        }
#pragma unroll
        for (int r = 0; r < 4; ++r) {
            float v = fmaxf(acc[r], 0.f);
            sh[(rowb + lg * 4 + r) * HSTR + n * 16 + lr] = f2bf(v);
        }
    }

    // ---- layer 2 (wave-local rows; no block barrier needed) ----
    short8v A2[4];
#pragma unroll
    for (int kk = 0; kk < 4; ++kk)
        A2[kk] = *reinterpret_cast<const short8v*>(&sh[(rowb + lr) * HSTR + kk * 32 + lg * 8]);
#pragma unroll
    for (int n = 0; n < 8; ++n) {
        float bv = b2[n * 16 + lr];
        f32x4 acc = {bv, bv, bv, bv};
#pragma unroll
        for (int kk = 0; kk < 4; ++kk) {
            short8v B = *reinterpret_cast<const short8v*>(&sw2[(n * 16 + lr) * HSTR + kk * 32 + lg * 8]);
            acc = __builtin_amdgcn_mfma_f32_16x16x32_bf16(A2[kk], B, acc, 0, 0, 0);
        }
#pragma unroll
        for (int r = 0; r < 4; ++r) {
            int grow = row0 + rowb + lg * 4 + r;
            if (grow < nrows)
                outp[(size_t)grow * D + n * 16 + lr] = acc[r];
        }
    }
}

// ===========================================================================
// Fallback: init + fp32 atomic scatter
// ===========================================================================
__global__ void init_kernel(const float* __restrict__ x, float* __restrict__ out, int n4) {
    int i = blockIdx.x * blockDim.x + threadIdx.x;
    if (i < n4) {
        reinterpret_cast<float4*>(out)[i] = reinterpret_cast<const float4*>(x)[i];
    }
}

__global__ void scatter_kernel(const float* __restrict__ x,
                               const int* __restrict__ ei,
                               float* __restrict__ out, int ne) {
    long long gid = (long long)blockIdx.x * blockDim.x + threadIdx.x;
    int e = (int)(gid >> 5);
    if (e >= ne) return;
    int d0 = ((int)gid & 31) * 4;
    int src = ei[e];
    int dst = ei[ne + e];
    float4 v = *reinterpret_cast<const float4*>(x + (long long)src * D + d0);
    float* o = out + (long long)dst * D + d0;
    atomicAdd(o + 0, v.x);
    atomicAdd(o + 1, v.y);
    atomicAdd(o + 2, v.z);
    atomicAdd(o + 3, v.w);
}

// ===========================================================================
// Fallback MLP: fp32 in-place row-tile GEMM
// ===========================================================================
template <bool RELU>
__global__ __launch_bounds__(MLP_THREADS, 1) void mlp_kernel(
    const float* __restrict__ in, const float* __restrict__ W,
    const float* __restrict__ b, float* __restrict__ outp, int nrows) {
    __shared__ float Wl[D][D];
    __shared__ float inl[TILE_ROWS][D + 4];

    const int tid = threadIdx.x;
    const int row0 = blockIdx.x * TILE_ROWS;

    for (int i = tid; i < D * D / 4; i += MLP_THREADS) {
        reinterpret_cast<float4*>(&Wl[0][0])[i] =
            reinterpret_cast<const float4*>(W)[i];
    }
    for (int i = tid; i < TILE_ROWS * (D / 4); i += MLP_THREADS) {
        int r = i >> 5;
        int k4 = i & 31;
        float4 v = make_float4(0.f, 0.f, 0.f, 0.f);
        if (row0 + r < nrows)
            v = *reinterpret_cast<const float4*>(in + (size_t)(row0 + r) * D + 4 * k4);
        *reinterpret_cast<float4*>(&inl[r][4 * k4]) = v;
    }
    __syncthreads();

    const int cg = tid & 31;
    const int rg = tid >> 5;
    const int c0 = cg * 4;
    const int r0 = rg * 4;

    float4 bv = *reinterpret_cast<const float4*>(b + c0);
    float acc[4][4];
#pragma unroll
    for (int i = 0; i < 4; ++i) {
        acc[i][0] = bv.x; acc[i][1] = bv.y; acc[i][2] = bv.z; acc[i][3] = bv.w;
    }

#pragma unroll 4
    for (int k4 = 0; k4 < 32; ++k4) {
        float4 w0 = *reinterpret_cast<const float4*>(&Wl[4 * k4 + 0][c0]);
        float4 w1 = *reinterpret_cast<const float4*>(&Wl[4 * k4 + 1][c0]);
        float4 w2 = *reinterpret_cast<const float4*>(&Wl[4 * k4 + 2][c0]);
        float4 w3 = *reinterpret_cast<const float4*>(&Wl[4 * k4 + 3][c0]);
#pragma unroll
        for (int i = 0; i < 4; ++i) {
            float4 a = *reinterpret_cast<const float4*>(&inl[r0 + i][4 * k4]);
            acc[i][0] += a.x * w0.x + a.y * w1.x + a.z * w2.x + a.w * w3.x;
            acc[i][1] += a.x * w0.y + a.y * w1.y + a.z * w2.y + a.w * w3.y;
            acc[i][2] += a.x * w0.z + a.y * w1.z + a.z * w2.z + a.w * w3.z;
            acc[i][3] += a.x * w0.w + a.y * w1.w + a.z * w2.w + a.w * w3.w;
        }
    }

#pragma unroll
    for (int i = 0; i < 4; ++i) {
        int r = row0 + r0 + i;
        if (r < nrows) {
            float4 o;
            if (RELU) {
                o.x = fmaxf(acc[i][0], 0.f); o.y = fmaxf(acc[i][1], 0.f);
                o.z = fmaxf(acc[i][2], 0.f); o.w = fmaxf(acc[i][3], 0.f);
            } else {
                o.x = acc[i][0]; o.y = acc[i][1]; o.z = acc[i][2]; o.w = acc[i][3];
            }
            *reinterpret_cast<float4*>(outp + (size_t)r * D + c0) = o;
        }
    }
}

extern "C" void kernel_launch(void* const* d_in, const int* in_sizes, int n_in,
                              void* d_out, int out_size, void* d_ws, size_t ws_size,
                              hipStream_t stream) {
    const float* x = (const float*)d_in[0];
    const int* ei = (const int*)d_in[1];
    const float* W1 = (const float*)d_in[2];
    const float* b1 = (const float*)d_in[3];
    const float* W2 = (const float*)d_in[4];
    const float* b2 = (const float*)d_in[5];
    float* out = (float*)d_out;

    const int nrows = in_sizes[0] / D;     // 100000 nodes
    const int ne = in_sizes[1] / 2;        // 3200000 edges
    const int nbkt = (nrows + BK_NODES - 1) / BK_NODES;

    // ws layout: [xh (bf tier)] | offsets[nrows+1] | sorted_src[ne] | pairs[ne]
    //            | ghist | cbase | ccursor | [W1t|W2t (mfma)] | [hbf (hbf tier)]
    size_t xh_bytes = (((size_t)nrows * D * sizeof(ushort_t)) + 15) & ~(size_t)15;
    size_t csr_bytes = ((size_t)(nrows + 1) + 2 * (size_t)ne + 3 * (size_t)nbkt + 1) * sizeof(int);
    size_t need_fp = csr_bytes;
    size_t need_bf = xh_bytes + csr_bytes;
    size_t wt_bytes = (size_t)D * HSTR * sizeof(ushort_t);   // 34816
    size_t wt_off = (need_bf + 15) & ~(size_t)15;
    size_t need_mfma = wt_off + 2 * wt_bytes;
    size_t hbf_off = (need_mfma + 15) & ~(size_t)15;
    size_t hbf_bytes = (size_t)nrows * D * sizeof(ushort_t);
    size_t need_hbf = hbf_off + hbf_bytes;

    const int hblocks = (ne + 256 * EPB - 1) / (256 * EPB);
    const int sblocks2 = (ne + SC_THREADS * SC_EPB - 1) / (SC_THREADS * SC_EPB);

    bool use_mfma = false;
    bool use_hbf = false;
    ushort_t* w1t = nullptr;
    ushort_t* w2t = nullptr;
    uint_t* hbf = nullptr;

    if (nbkt <= MAX_BKT && ws_size >= need_fp) {
        const bool bf = (ws_size >= need_bf);
        use_mfma = (ws_size >= need_mfma);
        use_hbf = bf && use_mfma && (ws_size >= need_hbf);
        char* wp = (char*)d_ws;
        ushort_t* xh = nullptr;
        if (bf) { xh = (ushort_t*)wp; wp += xh_bytes; }
        int* offsets = (int*)wp;
        int* sorted_src = offsets + (nrows + 1);
        int* pairs = sorted_src + ne;
        int* ghist = pairs + ne;
        int* cbase = ghist + nbkt;
        int* ccursor = cbase + (nbkt + 1);
        if (use_mfma) {
            w1t = (ushort_t*)((char*)d_ws + wt_off);
            w2t = (ushort_t*)((char*)d_ws + wt_off + wt_bytes);
        }
        if (use_hbf) hbf = (uint_t*)((char*)d_ws + hbf_off);

        if (bf) {
            int n4 = nrows * (D / 4);
            cast_kernel<<<(n4 + 255) / 256, 256, 0, stream>>>(x, xh, n4);
        }
        if (use_mfma)
            wprep_kernel<<<(D * D + 255) / 256, 256, 0, stream>>>(W1, W2, w1t, w2t);
        zero_kernel<<<(nbkt + 255) / 256, 256, 0, stream>>>(ghist, nbkt);
        coarse_hist_kernel<<<hblocks, 256, 0, stream>>>(ei + ne, ghist, ne, nbkt);
        coarse_scan_kernel<<<1, SCAN_THREADS, 0, stream>>>(ghist, cbase, ccursor,
                                                           offsets, nbkt, nrows, ne);
        coarse_scatter_kernel<<<sblocks2, SC_THREADS, 0, stream>>>(ei, ccursor, pairs, ne, nbkt);
        bucket_csr_kernel<<<nbkt, 256, 0, stream>>>(pairs, cbase, offsets, sorted_src, nrows);

        long long athreads = (long long)nrows * 64;
        int ablocks = (int)((athreads + 255) / 256);
        if (bf)
            agg_bf_kernel<<<ablocks, 256, 0, stream>>>(xh, sorted_src, offsets, out, hbf, nrows);
        else
            agg_fp_kernel<<<ablocks, 256, 0, stream>>>(x, sorted_src, offsets, out, nrows);
    } else {
        int n4 = nrows * (D / 4);
        init_kernel<<<(n4 + 255) / 256, 256, 0, stream>>>(x, out, n4);
        long long sthreads = (long long)ne * 32;
        scatter_kernel<<<(int)((sthreads + 255) / 256), 256, 0, stream>>>(x, ei, out, ne);
    }

    if (use_mfma) {
        int fblocks = (nrows + MLP_BM - 1) / MLP_BM;
        if (use_hbf)
            fused_mlp_kernel<true><<<fblocks, FMLP_THREADS, 0, stream>>>(
                out, hbf, w1t, w2t, b1, b2, out, nrows);
        else
            fused_mlp_kernel<false><<<fblocks, FMLP_THREADS, 0, stream>>>(
                out, nullptr, w1t, w2t, b1, b2, out, nrows);
    } else {
        int mblocks = (nrows + TILE_ROWS - 1) / TILE_ROWS;
        mlp_kernel<true><<<mblocks, MLP_THREADS, 0, stream>>>(out, W1, b1, out, nrows);
        mlp_kernel<false><<<mblocks, MLP_THREADS, 0, stream>>>(out, W2, b2, out, nrows);
    }
}

// Round 10
// 241.427 us; speedup vs baseline: 12.2448x; 1.0133x over previous
//
#include <hip/hip_runtime.h>

#define D 128
#define TILE_ROWS 64
#define MLP_THREADS 512
#define BK_NODES 128     // dst-nodes per coarse bucket
#define MAX_BKT 1024
#define EPB 16           // edges per thread in hist section
#define PRO_THREADS 256
#define CAST_VEC 4
#define SC_THREADS 512
#define SC_EPB 24        // 12288 edges per scatter block
#define BC_THREADS 512
#define CAPL 6144        // LDS staging capacity per bucket in bucket_csr
#define FMLP_THREADS 512
#define MLP_BM 128
#define HSTR 136         // padded LDS row stride (bf16 elems)

typedef unsigned short ushort_t;
typedef unsigned int uint_t;
typedef __attribute__((ext_vector_type(8))) short short8v;   // 8 bf16 (4 VGPR)
typedef __attribute__((ext_vector_type(4))) float f32x4;

__device__ __forceinline__ ushort_t f2bf(float f) {
    uint_t u = __float_as_uint(f);
    u = u + 0x7FFFu + ((u >> 16) & 1u);   // round-to-nearest-even
    return (ushort_t)(u >> 16);
}
__device__ __forceinline__ float bf_lo(uint_t u) { return __uint_as_float(u << 16); }
__device__ __forceinline__ float bf_hi(uint_t u) { return __uint_as_float(u & 0xffff0000u); }

// ===========================================================================
// prologue (grid-sectioned): [cast x->xh] || [coarse hist] || [wprep]
// ghist must be zeroed beforehand (hipMemsetAsync).
// ===========================================================================
__global__ __launch_bounds__(PRO_THREADS) void prologue_kernel(
    const float* __restrict__ x, ushort_t* __restrict__ xh, int n4, int cast_blocks,
    const int* __restrict__ dsts, int* __restrict__ ghist, int ne, int nbkt, int hist_blocks,
    const float* __restrict__ W1, const float* __restrict__ W2,
    ushort_t* __restrict__ w1t, ushort_t* __restrict__ w2t) {
    __shared__ int h[MAX_BKT];
    int b = blockIdx.x;
    if (b < cast_blocks) {
        int base = b * PRO_THREADS * CAST_VEC + threadIdx.x;
#pragma unroll
        for (int j = 0; j < CAST_VEC; ++j) {
            int i = base + j * PRO_THREADS;
            if (i < n4) {
                float4 v = reinterpret_cast<const float4*>(x)[i];
                ushort4 o;
                o.x = f2bf(v.x); o.y = f2bf(v.y); o.z = f2bf(v.z); o.w = f2bf(v.w);
                reinterpret_cast<ushort4*>(xh)[i] = o;
            }
        }
        return;
    }
    b -= cast_blocks;
    if (b < hist_blocks) {
        for (int k = threadIdx.x; k < nbkt; k += PRO_THREADS) h[k] = 0;
        __syncthreads();
        int base = b * PRO_THREADS * EPB;
        for (int j = 0; j < EPB; ++j) {
            int e = base + j * PRO_THREADS + threadIdx.x;
            if (e < ne) atomicAdd(&h[dsts[e] >> 7], 1);
        }
        __syncthreads();
        for (int k = threadIdx.x; k < nbkt; k += PRO_THREADS)
            if (h[k]) atomicAdd(&ghist[k], h[k]);
        return;
    }
    b -= hist_blocks;
    int i = b * PRO_THREADS + threadIdx.x;
    if (w1t != nullptr && i < D * D) {
        int c = i & 127, k = i >> 7;
        w1t[(size_t)c * HSTR + k] = f2bf(W1[(size_t)k * D + c]);
        w2t[(size_t)c * HSTR + k] = f2bf(W2[(size_t)k * D + c]);
    }
}

// ===========================================================================
// coarse_scatter: per-block redundant LDS scan of ghist gives cbase (block 0
// publishes it + offsets[nnodes]); reservations = cbase + zero-based ccursor.
// Then block-local counting sort into 48KB LDS stage, coalesced copy-out.
// pairs[] holds (src<<7)|(dst&127), grouped by coarse bucket (dst>>7).
// ===========================================================================
__global__ __launch_bounds__(SC_THREADS) void coarse_scatter_kernel(
    const int* __restrict__ ei, const int* __restrict__ ghist,
    int* __restrict__ cbase, int* __restrict__ ccursor,
    int* __restrict__ offsets, int* __restrict__ pairs,
    int ne, int nbkt, int nnodes) {
    __shared__ int h[MAX_BKT];
    __shared__ int cbl[MAX_BKT];
    __shared__ int lbase[MAX_BKT];
    __shared__ int gbase[MAX_BKT];
    __shared__ int lcur[MAX_BKT];
    __shared__ int stot[SC_THREADS];
    __shared__ int stage[SC_THREADS * SC_EPB];   // 48 KB

    const int t = threadIdx.x;
    const int base = blockIdx.x * SC_THREADS * SC_EPB;

    // (A) global coarse-bucket scan (redundant per block)
    int g0 = (2 * t < nbkt) ? ghist[2 * t] : 0;
    int g1 = (2 * t + 1 < nbkt) ? ghist[2 * t + 1] : 0;
    stot[t] = g0 + g1;
    __syncthreads();
    for (int off = 1; off < SC_THREADS; off <<= 1) {
        int u = (t >= off) ? stot[t - off] : 0;
        __syncthreads();
        stot[t] += u;
        __syncthreads();
    }
    {
        int ge = stot[t] - (g0 + g1);
        cbl[2 * t] = ge;
        cbl[2 * t + 1] = ge + g0;
        if (blockIdx.x == 0) {
            if (2 * t < nbkt) cbase[2 * t] = ge;
            if (2 * t + 1 < nbkt) cbase[2 * t + 1] = ge + g0;
            if (t == SC_THREADS - 1) { cbase[nbkt] = stot[t]; offsets[nnodes] = ne; }
        }
    }
    __syncthreads();

    // (B) block-local bucket histogram
    for (int k = t; k < MAX_BKT; k += SC_THREADS) h[k] = 0;
    __syncthreads();
    for (int j = 0; j < SC_EPB; ++j) {
        int e = base + j * SC_THREADS + t;
        if (e < ne) atomicAdd(&h[ei[ne + e] >> 7], 1);
    }
    __syncthreads();

    // (C) local scan for stage positions
    int a0 = h[2 * t], a1 = h[2 * t + 1];
    stot[t] = a0 + a1;
    __syncthreads();
    for (int off = 1; off < SC_THREADS; off <<= 1) {
        int u = (t >= off) ? stot[t - off] : 0;
        __syncthreads();
        stot[t] += u;
        __syncthreads();
    }
    int bexc = stot[t] - (a0 + a1);
    lbase[2 * t] = bexc;          lcur[2 * t] = bexc;
    lbase[2 * t + 1] = bexc + a0; lcur[2 * t + 1] = bexc + a0;
    __syncthreads();

    // (D) reserve global chunks: bucket base + zero-based cursor
    for (int k = t; k < MAX_BKT; k += SC_THREADS)
        gbase[k] = h[k] ? (cbl[k] + atomicAdd(&ccursor[k], h[k])) : 0;
    __syncthreads();

    // (E) place packed pairs into LDS staging
    for (int j = 0; j < SC_EPB; ++j) {
        int e = base + j * SC_THREADS + t;
        if (e < ne) {
            int dst = ei[ne + e];
            int src = ei[e];
            int k = dst >> 7;
            int pos = atomicAdd(&lcur[k], 1);
            stage[pos] = (src << 7) | (dst & (BK_NODES - 1));
        }
    }
    __syncthreads();

    // (F) per-bin contiguous copy-out (coalesced)
    const int lane = t & 63, w = t >> 6;
    for (int k = w; k < nbkt; k += (SC_THREADS / 64)) {
        int cnt = h[k];
        int lb = lbase[k], gb = gbase[k];
        for (int i = lane; i < cnt; i += 64)
            pairs[gb + i] = stage[lb + i];
    }
}

// ===========================================================================
// bucket_csr: per-node CSR within each coarse bucket (LDS counting sort,
// coalesced stream-out; scattered fallback if bucket > CAPL).
// ===========================================================================
__global__ __launch_bounds__(BC_THREADS) void bucket_csr_kernel(
    const int* __restrict__ pairs, const int* __restrict__ cbase,
    int* __restrict__ offsets, int* __restrict__ sorted_src, int nnodes) {
    __shared__ int h[BK_NODES];
    __shared__ int ex[BK_NODES];
    __shared__ int cur[BK_NODES];
    __shared__ int stage[CAPL];      // 24 KB
    int b = blockIdx.x;
    int t = threadIdx.x;
    int rbeg = cbase[b], rend = cbase[b + 1];
    int cnt = rend - rbeg;
    if (t < BK_NODES) h[t] = 0;
    __syncthreads();
    for (int i = rbeg + t; i < rend; i += blockDim.x)
        atomicAdd(&h[pairs[i] & (BK_NODES - 1)], 1);
    __syncthreads();
    if (t < BK_NODES) ex[t] = h[t];
    __syncthreads();
    for (int off = 1; off < BK_NODES; off <<= 1) {
        int u = (t >= off && t < BK_NODES) ? ex[t - off] : 0;
        __syncthreads();
        if (t < BK_NODES) ex[t] += u;
        __syncthreads();
    }
    const bool staged = (cnt <= CAPL);
    if (t < BK_NODES) {
        int e = ex[t] - h[t];
        cur[t] = staged ? e : rbeg + e;
        int node = b * BK_NODES + t;
        if (node < nnodes) offsets[node] = rbeg + e;
    }
    __syncthreads();
    if (staged) {
        for (int i = rbeg + t; i < rend; i += blockDim.x) {
            int p = pairs[i];
            int pos = atomicAdd(&cur[p & (BK_NODES - 1)], 1);
            stage[pos] = p >> 7;
        }
        __syncthreads();
        for (int i = t; i < cnt; i += blockDim.x)
            sorted_src[rbeg + i] = stage[i];
    } else {
        for (int i = rbeg + t; i < rend; i += blockDim.x) {
            int p = pairs[i];
            int pos = atomicAdd(&cur[p & (BK_NODES - 1)], 1);
            sorted_src[pos] = p >> 7;
        }
    }
}

// ===========================================================================
// agg (bf16): one wave per node; two src rows per load instruction (uint2).
// Output bf16 to hbf (if given) or fp32 to out.
// ===========================================================================
__global__ void agg_bf_kernel(const ushort_t* __restrict__ xh,
                              const int* __restrict__ sorted_src,
                              const int* __restrict__ offsets,
                              float* __restrict__ out,
                              uint_t* __restrict__ hbf, int nnodes) {
    int gid = blockIdx.x * blockDim.x + threadIdx.x;
    int node = gid >> 6;
    if (node >= nnodes) return;
    const int lane = threadIdx.x & 63;
    const int col = lane & 31;
    const int half = lane >> 5;
    const uint2* xp = reinterpret_cast<const uint2*>(xh);   // 32 uint2 per row
    int beg = offsets[node];
    int end = offsets[node + 1];

    float s0, s1, s2, s3;
    {
        uint2 u = xp[(size_t)node * 32 + col];
        if (half) { u.x = 0u; u.y = 0u; }     // self term counted once
        s0 = bf_lo(u.x); s1 = bf_hi(u.x);
        s2 = bf_lo(u.y); s3 = bf_hi(u.y);
    }

    int i = beg;
    for (; i + 16 <= end; i += 16) {
        uint2 v0 = xp[(size_t)sorted_src[i + 0 + half] * 32 + col];
        uint2 v1 = xp[(size_t)sorted_src[i + 2 + half] * 32 + col];
        uint2 v2 = xp[(size_t)sorted_src[i + 4 + half] * 32 + col];
        uint2 v3 = xp[(size_t)sorted_src[i + 6 + half] * 32 + col];
        uint2 v4 = xp[(size_t)sorted_src[i + 8 + half] * 32 + col];
        uint2 v5 = xp[(size_t)sorted_src[i + 10 + half] * 32 + col];
        uint2 v6 = xp[(size_t)sorted_src[i + 12 + half] * 32 + col];
        uint2 v7 = xp[(size_t)sorted_src[i + 14 + half] * 32 + col];
        s0 += bf_lo(v0.x) + bf_lo(v1.x) + bf_lo(v2.x) + bf_lo(v3.x) +
              bf_lo(v4.x) + bf_lo(v5.x) + bf_lo(v6.x) + bf_lo(v7.x);
        s1 += bf_hi(v0.x) + bf_hi(v1.x) + bf_hi(v2.x) + bf_hi(v3.x) +
              bf_hi(v4.x) + bf_hi(v5.x) + bf_hi(v6.x) + bf_hi(v7.x);
        s2 += bf_lo(v0.y) + bf_lo(v1.y) + bf_lo(v2.y) + bf_lo(v3.y) +
              bf_lo(v4.y) + bf_lo(v5.y) + bf_lo(v6.y) + bf_lo(v7.y);
        s3 += bf_hi(v0.y) + bf_hi(v1.y) + bf_hi(v2.y) + bf_hi(v3.y) +
              bf_hi(v4.y) + bf_hi(v5.y) + bf_hi(v6.y) + bf_hi(v7.y);
    }
    for (; i + 2 <= end; i += 2) {
        uint2 u = xp[(size_t)sorted_src[i + half] * 32 + col];
        s0 += bf_lo(u.x); s1 += bf_hi(u.x);
        s2 += bf_lo(u.y); s3 += bf_hi(u.y);
    }
    if (i < end && half == 0) {
        uint2 u = xp[(size_t)sorted_src[i] * 32 + col];
        s0 += bf_lo(u.x); s1 += bf_hi(u.x);
        s2 += bf_lo(u.y); s3 += bf_hi(u.y);
    }

    s0 += __shfl_xor(s0, 32);
    s1 += __shfl_xor(s1, 32);
    s2 += __shfl_xor(s2, 32);
    s3 += __shfl_xor(s3, 32);

    if (half == 0) {
        if (hbf) {
            uint_t lo = (uint_t)f2bf(s0) | ((uint_t)f2bf(s1) << 16);
            uint_t hi = (uint_t)f2bf(s2) | ((uint_t)f2bf(s3) << 16);
            uint2 o; o.x = lo; o.y = hi;
            reinterpret_cast<uint2*>(hbf)[(size_t)node * 32 + col] = o;
        } else {
            float4 o; o.x = s0; o.y = s1; o.z = s2; o.w = s3;
            reinterpret_cast<float4*>(out + (size_t)node * D)[col] = o;
        }
    }
}

// fp32 fallback agg: one wave/node, float2/lane, unroll x8
__global__ void agg_fp_kernel(const float* __restrict__ x,
                              const int* __restrict__ sorted_src,
                              const int* __restrict__ offsets,
                              float* __restrict__ out, int nnodes) {
    int gid = blockIdx.x * blockDim.x + threadIdx.x;
    int node = gid >> 6;
    if (node >= nnodes) return;
    int lane = threadIdx.x & 63;
    int beg = offsets[node];
    int end = offsets[node + 1];
    const float2* xp = reinterpret_cast<const float2*>(x);
    float2 a = xp[(size_t)node * 64 + lane];
    float sx = a.x, sy = a.y;
    int i = beg;
    for (; i + 8 <= end; i += 8) {
        int s0 = sorted_src[i + 0], s1 = sorted_src[i + 1];
        int s2 = sorted_src[i + 2], s3 = sorted_src[i + 3];
        int s4 = sorted_src[i + 4], s5 = sorted_src[i + 5];
        int s6 = sorted_src[i + 6], s7 = sorted_src[i + 7];
        float2 v0 = xp[(size_t)s0 * 64 + lane];
        float2 v1 = xp[(size_t)s1 * 64 + lane];
        float2 v2 = xp[(size_t)s2 * 64 + lane];
        float2 v3 = xp[(size_t)s3 * 64 + lane];
        float2 v4 = xp[(size_t)s4 * 64 + lane];
        float2 v5 = xp[(size_t)s5 * 64 + lane];
        float2 v6 = xp[(size_t)s6 * 64 + lane];
        float2 v7 = xp[(size_t)s7 * 64 + lane];
        sx += ((v0.x + v1.x) + (v2.x + v3.x)) + ((v4.x + v5.x) + (v6.x + v7.x));
        sy += ((v0.y + v1.y) + (v2.y + v3.y)) + ((v4.y + v5.y) + (v6.y + v7.y));
    }
    for (; i < end; ++i) {
        float2 v = xp[(size_t)sorted_src[i] * 64 + lane];
        sx += v.x;
        sy += v.y;
    }
    float2 o; o.x = sx; o.y = sy;
    reinterpret_cast<float2*>(out)[(size_t)node * 64 + lane] = o;
}

// ===========================================================================
// fused_mlp: out = relu(h@W1+b1)@W2+b2, bf16 MFMA.
// BF=true: h staged from hbf (bf16, direct copy). BF=false: from fp32 h.
// ===========================================================================
template <bool BF>
__global__ __launch_bounds__(FMLP_THREADS, 1) void fused_mlp_kernel(
    const float* __restrict__ h, const uint_t* __restrict__ hbf,
    const ushort_t* __restrict__ w1t, const ushort_t* __restrict__ w2t,
    const float* __restrict__ b1, const float* __restrict__ b2,
    float* __restrict__ outp, int nrows) {
    __shared__ ushort_t sh[MLP_BM * HSTR];
    __shared__ ushort_t sw1[D * HSTR];
    __shared__ ushort_t sw2[D * HSTR];
    const int tid = threadIdx.x;
    const int row0 = blockIdx.x * MLP_BM;

    {
        const uint4* s1 = reinterpret_cast<const uint4*>(w1t);
        const uint4* s2 = reinterpret_cast<const uint4*>(w2t);
        uint4* d1 = reinterpret_cast<uint4*>(sw1);
        uint4* d2 = reinterpret_cast<uint4*>(sw2);
        for (int i = tid; i < D * HSTR / 8; i += FMLP_THREADS) { d1[i] = s1[i]; d2[i] = s2[i]; }
    }
    if (BF) {
        for (int i = tid; i < MLP_BM * 16; i += FMLP_THREADS) {
            int r = i >> 4, c = i & 15;
            uint4 v = make_uint4(0u, 0u, 0u, 0u);
            if (row0 + r < nrows)
                v = reinterpret_cast<const uint4*>(hbf + (size_t)(row0 + r) * 64)[c];
            *reinterpret_cast<uint4*>(&sh[r * HSTR + c * 8]) = v;
        }
    } else {
        for (int i = tid; i < MLP_BM * 32; i += FMLP_THREADS) {
            int r = i >> 5, c4 = i & 31;
            float4 v = make_float4(0.f, 0.f, 0.f, 0.f);
            if (row0 + r < nrows)
                v = reinterpret_cast<const float4*>(h + (size_t)(row0 + r) * D)[c4];
            ushort4 o;
            o.x = f2bf(v.x); o.y = f2bf(v.y); o.z = f2bf(v.z); o.w = f2bf(v.w);
            *reinterpret_cast<ushort4*>(&sh[r * HSTR + c4 * 4]) = o;
        }
    }
    __syncthreads();

    const int w = tid >> 6, l = tid & 63;
    const int lr = l & 15, lg = l >> 4;
    const int rowb = w * 16;

    // ---- layer 1 ----
    short8v A[4];
#pragma unroll
    for (int kk = 0; kk < 4; ++kk)
        A[kk] = *reinterpret_cast<const short8v*>(&sh[(rowb + lr) * HSTR + kk * 32 + lg * 8]);
#pragma unroll
    for (int n = 0; n < 8; ++n) {
        float bv = b1[n * 16 + lr];
        f32x4 acc = {bv, bv, bv, bv};
#pragma unroll
        for (int kk = 0; kk < 4; ++kk) {
            short8v B = *reinterpret_cast<const short8v*>(&sw1[(n * 16 + lr) * HSTR + kk * 32 + lg * 8]);
            acc = __builtin_amdgcn_mfma_f32_16x16x32_bf16(A[kk], B, acc, 0, 0, 0);
        }
#pragma unroll
        for (int r = 0; r < 4; ++r) {
            float v = fmaxf(acc[r], 0.f);
            sh[(rowb + lg * 4 + r) * HSTR + n * 16 + lr] = f2bf(v);
        }
    }

    // ---- layer 2 (wave-local rows; no block barrier needed) ----
    short8v A2[4];
#pragma unroll
    for (int kk = 0; kk < 4; ++kk)
        A2[kk] = *reinterpret_cast<const short8v*>(&sh[(rowb + lr) * HSTR + kk * 32 + lg * 8]);
#pragma unroll
    for (int n = 0; n < 8; ++n) {
        float bv = b2[n * 16 + lr];
        f32x4 acc = {bv, bv, bv, bv};
#pragma unroll
        for (int kk = 0; kk < 4; ++kk) {
            short8v B = *reinterpret_cast<const short8v*>(&sw2[(n * 16 + lr) * HSTR + kk * 32 + lg * 8]);
            acc = __builtin_amdgcn_mfma_f32_16x16x32_bf16(A2[kk], B, acc, 0, 0, 0);
        }
#pragma unroll
        for (int r = 0; r < 4; ++r) {
            int grow = row0 + rowb + lg * 4 + r;
            if (grow < nrows)
                outp[(size_t)grow * D + n * 16 + lr] = acc[r];
        }
    }
}

// ===========================================================================
// Fallback: init + fp32 atomic scatter
// ===========================================================================
__global__ void init_kernel(const float* __restrict__ x, float* __restrict__ out, int n4) {
    int i = blockIdx.x * blockDim.x + threadIdx.x;
    if (i < n4) {
        reinterpret_cast<float4*>(out)[i] = reinterpret_cast<const float4*>(x)[i];
    }
}

__global__ void scatter_kernel(const float* __restrict__ x,
                               const int* __restrict__ ei,
                               float* __restrict__ out, int ne) {
    long long gid = (long long)blockIdx.x * blockDim.x + threadIdx.x;
    int e = (int)(gid >> 5);
    if (e >= ne) return;
    int d0 = ((int)gid & 31) * 4;
    int src = ei[e];
    int dst = ei[ne + e];
    float4 v = *reinterpret_cast<const float4*>(x + (long long)src * D + d0);
    float* o = out + (long long)dst * D + d0;
    atomicAdd(o + 0, v.x);
    atomicAdd(o + 1, v.y);
    atomicAdd(o + 2, v.z);
    atomicAdd(o + 3, v.w);
}

// ===========================================================================
// Fallback MLP: fp32 in-place row-tile GEMM
// ===========================================================================
template <bool RELU>
__global__ __launch_bounds__(MLP_THREADS, 1) void mlp_kernel(
    const float* __restrict__ in, const float* __restrict__ W,
    const float* __restrict__ b, float* __restrict__ outp, int nrows) {
    __shared__ float Wl[D][D];
    __shared__ float inl[TILE_ROWS][D + 4];

    const int tid = threadIdx.x;
    const int row0 = blockIdx.x * TILE_ROWS;

    for (int i = tid; i < D * D / 4; i += MLP_THREADS) {
        reinterpret_cast<float4*>(&Wl[0][0])[i] =
            reinterpret_cast<const float4*>(W)[i];
    }
    for (int i = tid; i < TILE_ROWS * (D / 4); i += MLP_THREADS) {
        int r = i >> 5;
        int k4 = i & 31;
        float4 v = make_float4(0.f, 0.f, 0.f, 0.f);
        if (row0 + r < nrows)
            v = *reinterpret_cast<const float4*>(in + (size_t)(row0 + r) * D + 4 * k4);
        *reinterpret_cast<float4*>(&inl[r][4 * k4]) = v;
    }
    __syncthreads();

    const int cg = tid & 31;
    const int rg = tid >> 5;
    const int c0 = cg * 4;
    const int r0 = rg * 4;

    float4 bv = *reinterpret_cast<const float4*>(b + c0);
    float acc[4][4];
#pragma unroll
    for (int i = 0; i < 4; ++i) {
        acc[i][0] = bv.x; acc[i][1] = bv.y; acc[i][2] = bv.z; acc[i][3] = bv.w;
    }

#pragma unroll 4
    for (int k4 = 0; k4 < 32; ++k4) {
        float4 w0 = *reinterpret_cast<const float4*>(&Wl[4 * k4 + 0][c0]);
        float4 w1 = *reinterpret_cast<const float4*>(&Wl[4 * k4 + 1][c0]);
        float4 w2 = *reinterpret_cast<const float4*>(&Wl[4 * k4 + 2][c0]);
        float4 w3 = *reinterpret_cast<const float4*>(&Wl[4 * k4 + 3][c0]);
#pragma unroll
        for (int i = 0; i < 4; ++i) {
            float4 a = *reinterpret_cast<const float4*>(&inl[r0 + i][4 * k4]);
            acc[i][0] += a.x * w0.x + a.y * w1.x + a.z * w2.x + a.w * w3.x;
            acc[i][1] += a.x * w0.y + a.y * w1.y + a.z * w2.y + a.w * w3.y;
            acc[i][2] += a.x * w0.z + a.y * w1.z + a.z * w2.z + a.w * w3.z;
            acc[i][3] += a.x * w0.w + a.y * w1.w + a.z * w2.w + a.w * w3.w;
        }
    }

#pragma unroll
    for (int i = 0; i < 4; ++i) {
        int r = row0 + r0 + i;
        if (r < nrows) {
            float4 o;
            if (RELU) {
                o.x = fmaxf(acc[i][0], 0.f); o.y = fmaxf(acc[i][1], 0.f);
                o.z = fmaxf(acc[i][2], 0.f); o.w = fmaxf(acc[i][3], 0.f);
            } else {
                o.x = acc[i][0]; o.y = acc[i][1]; o.z = acc[i][2]; o.w = acc[i][3];
            }
            *reinterpret_cast<float4*>(outp + (size_t)r * D + c0) = o;
        }
    }
}

extern "C" void kernel_launch(void* const* d_in, const int* in_sizes, int n_in,
                              void* d_out, int out_size, void* d_ws, size_t ws_size,
                              hipStream_t stream) {
    const float* x = (const float*)d_in[0];
    const int* ei = (const int*)d_in[1];
    const float* W1 = (const float*)d_in[2];
    const float* b1 = (const float*)d_in[3];
    const float* W2 = (const float*)d_in[4];
    const float* b2 = (const float*)d_in[5];
    float* out = (float*)d_out;

    const int nrows = in_sizes[0] / D;     // 100000 nodes
    const int ne = in_sizes[1] / 2;        // 3200000 edges
    const int nbkt = (nrows + BK_NODES - 1) / BK_NODES;

    // ws layout: [xh (bf tier)] | offsets[nrows+1] | sorted_src[ne] | pairs[ne]
    //            | ghist | cbase | ccursor | [W1t|W2t (mfma)] | [hbf (hbf tier)]
    size_t xh_bytes = (((size_t)nrows * D * sizeof(ushort_t)) + 15) & ~(size_t)15;
    size_t csr_bytes = ((size_t)(nrows + 1) + 2 * (size_t)ne + 3 * (size_t)nbkt + 1) * sizeof(int);
    size_t need_fp = csr_bytes;
    size_t need_bf = xh_bytes + csr_bytes;
    size_t wt_bytes = (size_t)D * HSTR * sizeof(ushort_t);   // 34816
    size_t wt_off = (need_bf + 15) & ~(size_t)15;
    size_t need_mfma = wt_off + 2 * wt_bytes;
    size_t hbf_off = (need_mfma + 15) & ~(size_t)15;
    size_t hbf_bytes = (size_t)nrows * D * sizeof(ushort_t);
    size_t need_hbf = hbf_off + hbf_bytes;

    const int n4 = nrows * (D / 4);
    const int hist_blocks = (ne + PRO_THREADS * EPB - 1) / (PRO_THREADS * EPB);
    const int sc_blocks = (ne + SC_THREADS * SC_EPB - 1) / (SC_THREADS * SC_EPB);

    bool use_mfma = false;
    bool use_hbf = false;
    ushort_t* w1t = nullptr;
    ushort_t* w2t = nullptr;
    uint_t* hbf = nullptr;

    if (nbkt <= MAX_BKT && ws_size >= need_fp) {
        const bool bf = (ws_size >= need_bf);
        use_mfma = (ws_size >= need_mfma);
        use_hbf = bf && use_mfma && (ws_size >= need_hbf);
        char* wp = (char*)d_ws;
        ushort_t* xh = nullptr;
        if (bf) { xh = (ushort_t*)wp; wp += xh_bytes; }
        int* offsets = (int*)wp;
        int* sorted_src = offsets + (nrows + 1);
        int* pairs = sorted_src + ne;
        int* ghist = pairs + ne;
        int* cbase = ghist + nbkt;
        int* ccursor = cbase + (nbkt + 1);
        if (use_mfma) {
            w1t = (ushort_t*)((char*)d_ws + wt_off);
            w2t = (ushort_t*)((char*)d_ws + wt_off + wt_bytes);
        }
        if (use_hbf) hbf = (uint_t*)((char*)d_ws + hbf_off);

        // zero ghist + cbase + ccursor in one async memset (cbase overwritten later)
        hipMemsetAsync(ghist, 0, (size_t)(3 * nbkt + 1) * sizeof(int), stream);

        const int cast_blocks = bf ? (n4 + PRO_THREADS * CAST_VEC - 1) / (PRO_THREADS * CAST_VEC) : 0;
        const int wprep_blocks = use_mfma ? (D * D + PRO_THREADS - 1) / PRO_THREADS : 0;
        const int pro_blocks = cast_blocks + hist_blocks + wprep_blocks;
        prologue_kernel<<<pro_blocks, PRO_THREADS, 0, stream>>>(
            x, xh, n4, cast_blocks, ei + ne, ghist, ne, nbkt, hist_blocks,
            W1, W2, w1t, w2t);

        coarse_scatter_kernel<<<sc_blocks, SC_THREADS, 0, stream>>>(
            ei, ghist, cbase, ccursor, offsets, pairs, ne, nbkt, nrows);
        bucket_csr_kernel<<<nbkt, BC_THREADS, 0, stream>>>(pairs, cbase, offsets, sorted_src, nrows);

        long long athreads = (long long)nrows * 64;
        int ablocks = (int)((athreads + 255) / 256);
        if (bf)
            agg_bf_kernel<<<ablocks, 256, 0, stream>>>(xh, sorted_src, offsets, out, hbf, nrows);
        else
            agg_fp_kernel<<<ablocks, 256, 0, stream>>>(x, sorted_src, offsets, out, nrows);
    } else {
        init_kernel<<<(n4 + 255) / 256, 256, 0, stream>>>(x, out, n4);
        long long sthreads = (long long)ne * 32;
        scatter_kernel<<<(int)((sthreads + 255) / 256), 256, 0, stream>>>(x, ei, out, ne);
    }

    if (use_mfma) {
        int fblocks = (nrows + MLP_BM - 1) / MLP_BM;
        if (use_hbf)
            fused_mlp_kernel<true><<<fblocks, FMLP_THREADS, 0, stream>>>(
                out, hbf, w1t, w2t, b1, b2, out, nrows);
        else
            fused_mlp_kernel<false><<<fblocks, FMLP_THREADS, 0, stream>>>(
                out, nullptr, w1t, w2t, b1, b2, out, nrows);
    } else {
        int mblocks = (nrows + TILE_ROWS - 1) / TILE_ROWS;
        mlp_kernel<true><<<mblocks, MLP_THREADS, 0, stream>>>(out, W1, b1, out, nrows);
        mlp_kernel<false><<<mblocks, MLP_THREADS, 0, stream>>>(out, W2, b2, out, nrows);
    }
}